// Round 9
// baseline (84.662 us; speedup 1.0000x reference)
//
#include <hip/hip_runtime.h>
#include <cstdint>

#define EPSF 1e-5f

typedef __attribute__((ext_vector_type(8))) short     bf16x8;
typedef __attribute__((ext_vector_type(4))) float     f32x4;
typedef __attribute__((ext_vector_type(2))) float     f32x2;
typedef __attribute__((ext_vector_type(4))) unsigned int uint32x4;
typedef __attribute__((ext_vector_type(2))) unsigned int uint32x2;

// ---- workspace layout ----
// floats (at byte 0): B0[64] @0, BC[64] @64, BF[64] @128, WC[9][64] @192  (ends 768 floats)
#define WS_B0 0
#define WS_BC 64
#define WS_BF 128
#define WS_WC 192
// bf16 A-fragments: wsA1 at byte 4096 (24 frags * 64 lanes * 8 = 12288 ushort)
//                   wsA2 at byte 28672 (16 frags * 64 lanes * 8 =  8192 ushort)

__device__ __forceinline__ unsigned short f2bf(float f) {
    union { float f; unsigned u; } v; v.f = f;
    unsigned r = v.u + 0x7fffu + ((v.u >> 16) & 1u);   // RNE
    return (unsigned short)(r >> 16);
}

// packed f32x2 -> bf16x2 (RNE), single HW instruction on gfx950
__device__ __forceinline__ unsigned cvtpk(float lo, float hi) {
    unsigned r;
    asm("v_cvt_pk_bf16_f32 %0, %1, %2" : "=v"(r) : "v"(lo), "v"(hi));
    return r;
}

// ---- packed-FP32 (VOP3P dual-issue) helpers; gfx90a+/gfx950 ----
__device__ __forceinline__ f32x2 pk_mul(f32x2 a, f32x2 b) {
    f32x2 d; asm("v_pk_mul_f32 %0, %1, %2" : "=v"(d) : "v"(a), "v"(b)); return d;
}
__device__ __forceinline__ f32x2 pk_add(f32x2 a, f32x2 b) {
    f32x2 d; asm("v_pk_add_f32 %0, %1, %2" : "=v"(d) : "v"(a), "v"(b)); return d;
}
__device__ __forceinline__ f32x2 pk_fma(f32x2 a, f32x2 b, f32x2 c) {
    f32x2 d; asm("v_pk_fma_f32 %0, %1, %2, %3" : "=v"(d) : "v"(a), "v"(b), "v"(c)); return d;
}
__device__ __forceinline__ f32x2 bc2(float s) { return (f32x2){s, s}; }

// ---------------- prep: fold BNs, collapse W_ps@{W_ssig,W_tsig}, pack MFMA A-frags ----------------
__global__ __launch_bounds__(64) void stem_prep(
    const float* __restrict__ W_ssig, const float* __restrict__ b_ssig,
    const float* __restrict__ W_tsig, const float* __restrict__ b_tsig,
    const float* __restrict__ W_raw,  const float* __restrict__ b_raw,
    const float* __restrict__ W_ps,   const float* __restrict__ b_ps,
    const float* __restrict__ W_fu,   const float* __restrict__ b_fu,
    const float* __restrict__ g_raw, const float* __restrict__ be_raw,
    const float* __restrict__ m_raw, const float* __restrict__ v_raw,
    const float* __restrict__ g_ps,  const float* __restrict__ be_ps,
    const float* __restrict__ m_ps,  const float* __restrict__ v_ps,
    const float* __restrict__ g_fu,  const float* __restrict__ be_fu,
    const float* __restrict__ m_fu,  const float* __restrict__ v_fu,
    float* __restrict__ wsf, unsigned short* __restrict__ wsA1,
    unsigned short* __restrict__ wsA2)
{
    const int l = threadIdx.x;         // 0..63
    const int f = blockIdx.x;
    if (f < 24) {
        // A1 frag f = h*12 + s*4 + to ; element b: W1[k=s*32+8*(l>>4)+b][o=to*16+(l&15)]
        const int h = f / 12, rem = f % 12, s = rem / 4, to = rem % 4;
        const int o = to*16 + (l & 15);
        const float sps = g_ps[o] / sqrtf(v_ps[o] + EPSF);
        const float* wp  = W_ps + o*128 + 64*h;
        const float* wsg = h ? W_tsig : W_ssig;
        for (int b = 0; b < 8; ++b) {
            const int k = s*32 + ((l >> 4) * 8) + b;
            float v = 0.f;
            if (k < 84) {
                float acc = 0.f;
                for (int c = 0; c < 64; ++c) acc = fmaf(wp[c], wsg[c*84 + k], acc);
                v = acc * sps;
            }
            wsA1[f*512 + l*8 + b] = f2bf(v);
        }
    } else if (f < 40) {
        // A2 frag q = s*4+to ; element b: Wf[c=s*32+8*(l>>4)+b][o] = sfu[o]*W_fu[o*128+c]
        const int q = f - 24, s = q / 4, to = q % 4;
        const int o = to*16 + (l & 15);
        const float sfu = g_fu[o] / sqrtf(v_fu[o] + EPSF);
        for (int b = 0; b < 8; ++b) {
            const int c = s*32 + ((l >> 4) * 8) + b;
            wsA2[q*512 + l*8 + b] = f2bf(W_fu[o*128 + c] * sfu);
        }
    } else {
        const int o = l;
        const float sps = g_ps[o] / sqrtf(v_ps[o] + EPSF);
        float acc = b_ps[o] - m_ps[o];
        for (int c = 0; c < 64; ++c) {
            acc = fmaf(W_ps[o*128 + c],      b_ssig[c], acc);
            acc = fmaf(W_ps[o*128 + 64 + c], b_tsig[c], acc);
        }
        wsf[WS_B0 + o] = acc * sps + be_ps[o];
        const float sraw = g_raw[o] / sqrtf(v_raw[o] + EPSF);
        wsf[WS_BC + o] = (b_raw[o] - m_raw[o]) * sraw + be_raw[o];
        const float sfu = g_fu[o] / sqrtf(v_fu[o] + EPSF);
        wsf[WS_BF + o] = (b_fu[o] - m_fu[o]) * sfu + be_fu[o];
        // conv weights in [i][o] layout so adjacent channels pair for packed math
        for (int i = 0; i < 9; ++i) wsf[WS_WC + i*64 + o] = W_raw[o*9 + i] * sraw;
    }
}

// ---- packed depth-3 signature step; state pairs along last index:
// S1[p]=(s1_{2p},s1_{2p+1}); S2[i*2+jp]; S3[(i*4+j)*2+kp]. Uses OLD S2,S1 (order matters).
__device__ __forceinline__ void sig_step_pk(f32x2* __restrict__ S1, f32x2* __restrict__ S2,
                                            f32x2* __restrict__ S3,
                                            float d0, float d1, float d2, float d3)
{
    const f32x2 d01 = {d0, d1}, d23 = {d2, d3};
    const f32x2 hh  = {0.5f, 0.5f}, tt3 = {1.f/3.f, 1.f/3.f};
    const f32x2 dh01 = pk_mul(hh, d01), dh23 = pk_mul(hh, d23);
    const float dhs[4] = { dh01.x, dh01.y, dh23.x, dh23.y };
    f32x2 e2[8];
#pragma unroll
    for (int i = 0; i < 4; ++i) {
        const f32x2 dhb = bc2(dhs[i]);
        e2[i*2+0] = pk_mul(dhb, d01);
        e2[i*2+1] = pk_mul(dhb, d23);
    }
    const f32x2 fv01 = pk_fma(d01, tt3, S1[0]);
    const f32x2 fv23 = pk_fma(d23, tt3, S1[1]);
    const float fvs[4] = { fv01.x, fv01.y, fv23.x, fv23.y };
#pragma unroll
    for (int i = 0; i < 4; ++i) {
        const f32x2 fib = bc2(fvs[i]);
#pragma unroll
        for (int j = 0; j < 4; ++j) {
            const f32x2 s2p = S2[i*2 + (j>>1)];
            const f32x2 s2b = bc2((j & 1) ? s2p.y : s2p.x);
            const int base = (i*4+j)*2;
            S3[base+0] = pk_fma(s2b, d01, pk_fma(fib, e2[j*2+0], S3[base+0]));
            S3[base+1] = pk_fma(s2b, d23, pk_fma(fib, e2[j*2+1], S3[base+1]));
        }
    }
    const float s1s[4] = { S1[0].x, S1[0].y, S1[1].x, S1[1].y };
#pragma unroll
    for (int i = 0; i < 4; ++i) {
        const f32x2 s1b = bc2(s1s[i]);
        S2[i*2+0] = pk_fma(s1b, d01, pk_add(S2[i*2+0], e2[i*2+0]));
        S2[i*2+1] = pk_fma(s1b, d23, pk_add(S2[i*2+1], e2[i*2+1]));
    }
    S1[0] = pk_add(S1[0], d01);
    S1[1] = pk_add(S1[1], d23);
}

// first step from zero state with d3==0: S1=d, S2=e2, S3=(d_i/3) * e2[j][k]
__device__ __forceinline__ void sig_init_pk(f32x2* __restrict__ S1, f32x2* __restrict__ S2,
                                            f32x2* __restrict__ S3,
                                            float d0, float d1, float d2)
{
    const f32x2 d01 = {d0, d1}, d23 = {d2, 0.f};
    const f32x2 hh  = {0.5f, 0.5f}, tt3 = {1.f/3.f, 1.f/3.f};
    const f32x2 dh01 = pk_mul(hh, d01), dh23 = pk_mul(hh, d23);
    const float dhs[4] = { dh01.x, dh01.y, dh23.x, 0.f };
    S1[0] = d01; S1[1] = d23;
#pragma unroll
    for (int i = 0; i < 4; ++i) {
        const f32x2 dhb = bc2(dhs[i]);
        S2[i*2+0] = pk_mul(dhb, d01);
        S2[i*2+1] = pk_mul(dhb, d23);
    }
    const f32x2 d3_01 = pk_mul(tt3, d01), d3_23 = pk_mul(tt3, d23);
    const float d3s[4] = { d3_01.x, d3_01.y, d3_23.x, 0.f };
#pragma unroll
    for (int i = 0; i < 4; ++i) {
        const f32x2 db = bc2(d3s[i]);
#pragma unroll
        for (int j = 0; j < 4; ++j) {
            S3[(i*4+j)*2+0] = pk_mul(db, S2[j*2+0]);
            S3[(i*4+j)*2+1] = pk_mul(db, S2[j*2+1]);
        }
    }
}

// pack paired sig state (84 vals + 12 zero pad -> 48 u32 of bf16x2), linear k order
__device__ __forceinline__ void sig_pack(const f32x2* __restrict__ S1, const f32x2* __restrict__ S2,
                                         const f32x2* __restrict__ S3, unsigned* __restrict__ uu)
{
    uu[0] = cvtpk(S1[0].x, S1[0].y);
    uu[1] = cvtpk(S1[1].x, S1[1].y);
#pragma unroll
    for (int p = 0; p < 8; ++p)  uu[2+p]  = cvtpk(S2[p].x, S2[p].y);
#pragma unroll
    for (int p = 0; p < 32; ++p) uu[10+p] = cvtpk(S3[p].x, S3[p].y);
#pragma unroll
    for (int i = 42; i < 48; ++i) uu[i] = 0u;
}

// grid: (4 t-chunks, 64 j, 32 b); block 64 = 1 wave; block owns t-cols [bx*64, bx*64+64).
// k-major LDS: slot s (16B per row) at byte s*1024 + row*16; 12 slots = 12288 B.
// PHASE ORDER avoids sig(f32) x acc(64 AGPR) live overlap (round-7 spill lesson):
//   sigma_s -> LDS; sigma_t -> 42 packed u32 REGS; GEMM1a; dump sigma_t -> LDS; GEMM1b.
// Explicit __syncthreads() at every LDS W->R / R->W boundary (round-4 lesson).
__global__ __launch_bounds__(64, 3) void stem_main(
    const float* __restrict__ x, const int* __restrict__ path,
    const float* __restrict__ wsf, const unsigned short* __restrict__ wsA1,
    const unsigned short* __restrict__ wsA2, float* __restrict__ out)
{
    __shared__ char sb[12 * 1024];
    const int l  = threadIdx.x;                  // lane
    const int t  = blockIdx.x * 64 + l;          // global t for this thread's column
    const int j  = blockIdx.y;
    const int b  = blockIdx.z;
    const float* xb = x + (size_t)b * (3*64*256);

    const int lg = l >> 4;      // lane k-group
    const int li = l & 15;      // m/n index within tile
    char* const myw = sb + l*16;                 // write base: slot via immediate

    f32x2 S1[2], S2[8], S3[32];

    // ---- sigma_s: step-1 specialized, then 4 general steps (d3 = 0.25 literal) ----
    {
        int jp = path[j*5 + 0];
        float pr0 = xb[(0*64 + jp)*256 + t];
        float pr1 = xb[(1*64 + jp)*256 + t];
        float pr2 = xb[(2*64 + jp)*256 + t];
        sig_init_pk(S1, S2, S3, pr0, pr1, pr2);
#pragma unroll
        for (int s = 1; s < 5; ++s) {
            jp = path[j*5 + s];
            const float p0 = xb[(0*64 + jp)*256 + t];
            const float p1 = xb[(1*64 + jp)*256 + t];
            const float p2 = xb[(2*64 + jp)*256 + t];
            sig_step_pk(S1, S2, S3, p0-pr0, p1-pr1, p2-pr2, 0.25f);
            pr0=p0; pr1=p1; pr2=p2;
        }
    }
    // pack sigma_s k-major to LDS: slot v holds sig[8v..8v+7] (bf16), rows = lanes
    {
        unsigned uu[48];
        sig_pack(S1, S2, S3, uu);
#pragma unroll
        for (int v = 0; v < 12; ++v) {
            uint32x4 w = { uu[4*v], uu[4*v+1], uu[4*v+2], uu[4*v+3] };
            *(uint32x4*)(myw + v*1024) = w;
        }
    }
    __syncthreads();                                      // W->R: sigma_s ready

    // ---- sigma_t NOW (before acc is born): scrambled window; result packed to regs ----
    unsigned uuT[48];
    {
        int idx  = j*7;
        int jsrc = idx & 63, tl = idx >> 6;
        int ts   = min(max(t + tl - 3, 0), 255);
        float pr0 = xb[(0*64 + jsrc)*256 + ts];
        float pr1 = xb[(1*64 + jsrc)*256 + ts];
        float pr2 = xb[(2*64 + jsrc)*256 + ts];
        sig_init_pk(S1, S2, S3, pr0, pr1, pr2);
#pragma unroll
        for (int k = 1; k < 7; ++k) {
            idx = j*7 + k; jsrc = idx & 63; tl = idx >> 6;
            ts = min(max(t + tl - 3, 0), 255);
            const float p0 = xb[(0*64 + jsrc)*256 + ts];
            const float p1 = xb[(1*64 + jsrc)*256 + ts];
            const float p2 = xb[(2*64 + jsrc)*256 + ts];
            sig_step_pk(S1, S2, S3, p0-pr0, p1-pr1, p2-pr2, (1.f/6.f));
            pr0=p0; pr1=p1; pr2=p2;
        }
        sig_pack(S1, S2, S3, uuT);
    }
    // sig state (f32) is DEAD here -> acc can use the freed registers

    // ---- GEMM1a: acc = B0 + A(h=0) * sigma_s ----
    f32x4 acc[4][4];
#pragma unroll
    for (int to = 0; to < 4; ++to) {
        const f32x4 b0 = *(const f32x4*)(wsf + WS_B0 + to*16 + lg*4);
#pragma unroll
        for (int tt = 0; tt < 4; ++tt) acc[to][tt] = b0;
    }
    {
#pragma unroll
        for (int s = 0; s < 3; ++s) {
            bf16x8 A0 = *(const bf16x8*)(wsA1 + ((0*3+s)*4+0)*512 + l*8);
            bf16x8 A1 = *(const bf16x8*)(wsA1 + ((0*3+s)*4+1)*512 + l*8);
            bf16x8 A2 = *(const bf16x8*)(wsA1 + ((0*3+s)*4+2)*512 + l*8);
            bf16x8 A3 = *(const bf16x8*)(wsA1 + ((0*3+s)*4+3)*512 + l*8);
#pragma unroll
            for (int tt = 0; tt < 4; ++tt) {
                const bf16x8 B = *(const bf16x8*)(sb + (s*4+lg)*1024 + (tt*16+li)*16);
                acc[0][tt] = __builtin_amdgcn_mfma_f32_16x16x32_bf16(A0, B, acc[0][tt], 0, 0, 0);
                acc[1][tt] = __builtin_amdgcn_mfma_f32_16x16x32_bf16(A1, B, acc[1][tt], 0, 0, 0);
                acc[2][tt] = __builtin_amdgcn_mfma_f32_16x16x32_bf16(A2, B, acc[2][tt], 0, 0, 0);
                acc[3][tt] = __builtin_amdgcn_mfma_f32_16x16x32_bf16(A3, B, acc[3][tt], 0, 0, 0);
            }
        }
    }
    __syncthreads();                                      // R->W: done reading sigma_s

    // dump packed sigma_t regs -> LDS
    {
#pragma unroll
        for (int v = 0; v < 12; ++v) {
            uint32x4 w = { uuT[4*v], uuT[4*v+1], uuT[4*v+2], uuT[4*v+3] };
            *(uint32x4*)(myw + v*1024) = w;
        }
    }
    __syncthreads();                                      // W->R: sigma_t ready

    // conv window loads issued here (HBM latency hides under GEMM1b + ps pack)
    float xv[9];
#pragma unroll
    for (int ci = 0; ci < 3; ++ci) {
        const float* xr = xb + (ci*64 + j)*256;
        xv[ci*3+0] = (t >= 1)   ? xr[t-1] : 0.f;
        xv[ci*3+1] = xr[t];
        xv[ci*3+2] = (t <= 254) ? xr[t+1] : 0.f;
    }

    // ---- GEMM1b: acc += A(h=1) * sigma_t ----
    {
#pragma unroll
        for (int s = 0; s < 3; ++s) {
            bf16x8 A0 = *(const bf16x8*)(wsA1 + ((1*3+s)*4+0)*512 + l*8);
            bf16x8 A1 = *(const bf16x8*)(wsA1 + ((1*3+s)*4+1)*512 + l*8);
            bf16x8 A2 = *(const bf16x8*)(wsA1 + ((1*3+s)*4+2)*512 + l*8);
            bf16x8 A3 = *(const bf16x8*)(wsA1 + ((1*3+s)*4+3)*512 + l*8);
#pragma unroll
            for (int tt = 0; tt < 4; ++tt) {
                const bf16x8 B = *(const bf16x8*)(sb + (s*4+lg)*1024 + (tt*16+li)*16);
                acc[0][tt] = __builtin_amdgcn_mfma_f32_16x16x32_bf16(A0, B, acc[0][tt], 0, 0, 0);
                acc[1][tt] = __builtin_amdgcn_mfma_f32_16x16x32_bf16(A1, B, acc[1][tt], 0, 0, 0);
                acc[2][tt] = __builtin_amdgcn_mfma_f32_16x16x32_bf16(A2, B, acc[2][tt], 0, 0, 0);
                acc[3][tt] = __builtin_amdgcn_mfma_f32_16x16x32_bf16(A3, B, acc[3][tt], 0, 0, 0);
            }
        }
    }
    __syncthreads();                                      // R->W: done reading sigma_t

    // ---- ps pack: u_ps[row][o] = bf16(relu(acc)), k-major (slot = o>>3) ----
#pragma unroll
    for (int to = 0; to < 4; ++to) {
#pragma unroll
        for (int tt = 0; tt < 4; ++tt) {
            const unsigned w0 = cvtpk(fmaxf(acc[to][tt][0], 0.f), fmaxf(acc[to][tt][1], 0.f));
            const unsigned w1 = cvtpk(fmaxf(acc[to][tt][2], 0.f), fmaxf(acc[to][tt][3], 0.f));
            uint32x2 w = { w0, w1 };
            *(uint32x2*)(sb + (to*2+(lg>>1))*1024 + (tt*16+li)*16 + ((lg&1)<<3)) = w;
        }
    }

    // ---- conv into cu regs (packed over adjacent channel pairs; no LDS) ----
    unsigned cu[32];
    {
        f32x2 xvb[9];
#pragma unroll
        for (int i = 0; i < 9; ++i) xvb[i] = bc2(xv[i]);
#pragma unroll
        for (int cc = 0; cc < 32; ++cc) {
            f32x2 a = *(const f32x2*)(wsf + WS_BC + 2*cc);
#pragma unroll
            for (int i = 0; i < 9; ++i)
                a = pk_fma(xvb[i], *(const f32x2*)(wsf + WS_WC + i*64 + 2*cc), a);
            cu[cc] = cvtpk(fmaxf(a.x, 0.f), fmaxf(a.y, 0.f));
        }
    }
    __syncthreads();                                      // W->R: u_ps ready

    // ---- GEMM2-ps: acc = BF + Wf_hi^T u_ps  (A2 frags q = 8..15) ----
#pragma unroll
    for (int to = 0; to < 4; ++to) {
        const f32x4 bf4 = *(const f32x4*)(wsf + WS_BF + to*16 + lg*4);
#pragma unroll
        for (int tt = 0; tt < 4; ++tt) acc[to][tt] = bf4;
    }
    {
#pragma unroll
        for (int s = 0; s < 2; ++s) {
            bf16x8 A0 = *(const bf16x8*)(wsA2 + ((s+2)*4+0)*512 + l*8);
            bf16x8 A1 = *(const bf16x8*)(wsA2 + ((s+2)*4+1)*512 + l*8);
            bf16x8 A2 = *(const bf16x8*)(wsA2 + ((s+2)*4+2)*512 + l*8);
            bf16x8 A3 = *(const bf16x8*)(wsA2 + ((s+2)*4+3)*512 + l*8);
#pragma unroll
            for (int tt = 0; tt < 4; ++tt) {
                const bf16x8 B = *(const bf16x8*)(sb + (s*4+lg)*1024 + (tt*16+li)*16);
                acc[0][tt] = __builtin_amdgcn_mfma_f32_16x16x32_bf16(A0, B, acc[0][tt], 0, 0, 0);
                acc[1][tt] = __builtin_amdgcn_mfma_f32_16x16x32_bf16(A1, B, acc[1][tt], 0, 0, 0);
                acc[2][tt] = __builtin_amdgcn_mfma_f32_16x16x32_bf16(A2, B, acc[2][tt], 0, 0, 0);
                acc[3][tt] = __builtin_amdgcn_mfma_f32_16x16x32_bf16(A3, B, acc[3][tt], 0, 0, 0);
            }
        }
    }
    __syncthreads();                                      // R->W: done reading u_ps

    // ---- conv store: u_conv[row][c], own row, k-major ----
    {
#pragma unroll
        for (int v = 0; v < 8; ++v) {
            uint32x4 w = { cu[4*v], cu[4*v+1], cu[4*v+2], cu[4*v+3] };
            *(uint32x4*)(myw + v*1024) = w;
        }
    }
    __syncthreads();                                      // W->R: u_conv ready

    // ---- GEMM2-conv: acc += Wf_lo^T u_conv  (A2 frags q = 0..7) ----
    {
#pragma unroll
        for (int s = 0; s < 2; ++s) {
            bf16x8 A0 = *(const bf16x8*)(wsA2 + (s*4+0)*512 + l*8);
            bf16x8 A1 = *(const bf16x8*)(wsA2 + (s*4+1)*512 + l*8);
            bf16x8 A2 = *(const bf16x8*)(wsA2 + (s*4+2)*512 + l*8);
            bf16x8 A3 = *(const bf16x8*)(wsA2 + (s*4+3)*512 + l*8);
#pragma unroll
            for (int tt = 0; tt < 4; ++tt) {
                const bf16x8 B = *(const bf16x8*)(sb + (s*4+lg)*1024 + (tt*16+li)*16);
                acc[0][tt] = __builtin_amdgcn_mfma_f32_16x16x32_bf16(A0, B, acc[0][tt], 0, 0, 0);
                acc[1][tt] = __builtin_amdgcn_mfma_f32_16x16x32_bf16(A1, B, acc[1][tt], 0, 0, 0);
                acc[2][tt] = __builtin_amdgcn_mfma_f32_16x16x32_bf16(A2, B, acc[2][tt], 0, 0, 0);
                acc[3][tt] = __builtin_amdgcn_mfma_f32_16x16x32_bf16(A3, B, acc[3][tt], 0, 0, 0);
            }
        }
    }

    // ---- final epilogue: relu (bias already in C-init), store out[b][o][j][t] ----
#pragma unroll
    for (int to = 0; to < 4; ++to) {
#pragma unroll
        for (int tt = 0; tt < 4; ++tt) {
            const int tg = blockIdx.x*64 + tt*16 + li;
#pragma unroll
            for (int r = 0; r < 4; ++r) {
                const int o = to*16 + lg*4 + r;
                out[(((size_t)b*64 + o)*64 + j)*256 + tg] = fmaxf(acc[to][tt][r], 0.f);
            }
        }
    }
}

extern "C" void kernel_launch(void* const* d_in, const int* in_sizes, int n_in,
                              void* d_out, int out_size, void* d_ws, size_t ws_size,
                              hipStream_t stream)
{
    const float* x      = (const float*)d_in[0];
    const int*   path   = (const int*)  d_in[1];
    const float* W_ssig = (const float*)d_in[2];
    const float* b_ssig = (const float*)d_in[3];
    const float* W_tsig = (const float*)d_in[4];
    const float* b_tsig = (const float*)d_in[5];
    const float* W_raw  = (const float*)d_in[6];
    const float* b_raw  = (const float*)d_in[7];
    const float* W_ps   = (const float*)d_in[8];
    const float* b_ps   = (const float*)d_in[9];
    const float* W_fu   = (const float*)d_in[10];
    const float* b_fu   = (const float*)d_in[11];
    const float* g_raw  = (const float*)d_in[12];
    const float* be_raw = (const float*)d_in[13];
    const float* m_raw  = (const float*)d_in[14];
    const float* v_raw  = (const float*)d_in[15];
    const float* g_ps   = (const float*)d_in[16];
    const float* be_ps  = (const float*)d_in[17];
    const float* m_ps   = (const float*)d_in[18];
    const float* v_ps   = (const float*)d_in[19];
    const float* g_fu   = (const float*)d_in[20];
    const float* be_fu  = (const float*)d_in[21];
    const float* m_fu   = (const float*)d_in[22];
    const float* v_fu   = (const float*)d_in[23];
    float* out = (float*)d_out;

    float*          wsf  = (float*)d_ws;
    unsigned short* wsA1 = (unsigned short*)((char*)d_ws + 4096);
    unsigned short* wsA2 = (unsigned short*)((char*)d_ws + 28672);

    stem_prep<<<41, 64, 0, stream>>>(W_ssig, b_ssig, W_tsig, b_tsig, W_raw, b_raw,
                                     W_ps, b_ps, W_fu, b_fu,
                                     g_raw, be_raw, m_raw, v_raw,
                                     g_ps, be_ps, m_ps, v_ps,
                                     g_fu, be_fu, m_fu, v_fu, wsf, wsA1, wsA2);

    dim3 grid(4, 64, 32);   // (t-chunks, J, B)
    stem_main<<<grid, 64, 0, stream>>>(x, path, wsf, wsA1, wsA2, out);
}

// Round 10
// 68.893 us; speedup vs baseline: 1.2289x; 1.2289x over previous
//
#include <hip/hip_runtime.h>
#include <cstdint>

#define EPSF 1e-5f

typedef __attribute__((ext_vector_type(8))) short     bf16x8;
typedef __attribute__((ext_vector_type(4))) float     f32x4;
typedef __attribute__((ext_vector_type(4))) unsigned int uint32x4;
typedef __attribute__((ext_vector_type(2))) unsigned int uint32x2;

// ---- workspace layout ----
// floats (at byte 0): B0[64] @0, BC[64] @64, BF[64] @128, WC[9][64] @192  (ends 768 floats)
#define WS_B0 0
#define WS_BC 64
#define WS_BF 128
#define WS_WC 192
// bf16 A-fragments: wsA1 at byte 4096 (24 frags * 64 lanes * 8 = 12288 ushort)
//                   wsA2 at byte 28672 (16 frags * 64 lanes * 8 =  8192 ushort)

__device__ __forceinline__ unsigned short f2bf(float f) {
    union { float f; unsigned u; } v; v.f = f;
    unsigned r = v.u + 0x7fffu + ((v.u >> 16) & 1u);   // RNE
    return (unsigned short)(r >> 16);
}

// packed f32x2 -> bf16x2 (RNE), single HW instruction on gfx950
__device__ __forceinline__ unsigned cvtpk(float lo, float hi) {
    unsigned r;
    asm("v_cvt_pk_bf16_f32 %0, %1, %2" : "=v"(r) : "v"(lo), "v"(hi));
    return r;
}

// ---------------- prep: fold BNs, collapse W_ps@{W_ssig,W_tsig}, pack MFMA A-frags ----------------
__global__ __launch_bounds__(64) void stem_prep(
    const float* __restrict__ W_ssig, const float* __restrict__ b_ssig,
    const float* __restrict__ W_tsig, const float* __restrict__ b_tsig,
    const float* __restrict__ W_raw,  const float* __restrict__ b_raw,
    const float* __restrict__ W_ps,   const float* __restrict__ b_ps,
    const float* __restrict__ W_fu,   const float* __restrict__ b_fu,
    const float* __restrict__ g_raw, const float* __restrict__ be_raw,
    const float* __restrict__ m_raw, const float* __restrict__ v_raw,
    const float* __restrict__ g_ps,  const float* __restrict__ be_ps,
    const float* __restrict__ m_ps,  const float* __restrict__ v_ps,
    const float* __restrict__ g_fu,  const float* __restrict__ be_fu,
    const float* __restrict__ m_fu,  const float* __restrict__ v_fu,
    float* __restrict__ wsf, unsigned short* __restrict__ wsA1,
    unsigned short* __restrict__ wsA2)
{
    const int l = threadIdx.x;         // 0..63
    const int f = blockIdx.x;
    if (f < 24) {
        // A1 frag f = h*12 + s*4 + to ; element b: W1[k=s*32+8*(l>>4)+b][o=to*16+(l&15)]
        const int h = f / 12, rem = f % 12, s = rem / 4, to = rem % 4;
        const int o = to*16 + (l & 15);
        const float sps = g_ps[o] / sqrtf(v_ps[o] + EPSF);
        const float* wp  = W_ps + o*128 + 64*h;
        const float* wsg = h ? W_tsig : W_ssig;
        for (int b = 0; b < 8; ++b) {
            const int k = s*32 + ((l >> 4) * 8) + b;
            float v = 0.f;
            if (k < 84) {
                float acc = 0.f;
                for (int c = 0; c < 64; ++c) acc = fmaf(wp[c], wsg[c*84 + k], acc);
                v = acc * sps;
            }
            wsA1[f*512 + l*8 + b] = f2bf(v);
        }
    } else if (f < 40) {
        // A2 frag q = s*4+to ; element b: Wf[c=s*32+8*(l>>4)+b][o] = sfu[o]*W_fu[o*128+c]
        const int q = f - 24, s = q / 4, to = q % 4;
        const int o = to*16 + (l & 15);
        const float sfu = g_fu[o] / sqrtf(v_fu[o] + EPSF);
        for (int b = 0; b < 8; ++b) {
            const int c = s*32 + ((l >> 4) * 8) + b;
            wsA2[q*512 + l*8 + b] = f2bf(W_fu[o*128 + c] * sfu);
        }
    } else {
        const int o = l;
        const float sps = g_ps[o] / sqrtf(v_ps[o] + EPSF);
        float acc = b_ps[o] - m_ps[o];
        for (int c = 0; c < 64; ++c) {
            acc = fmaf(W_ps[o*128 + c],      b_ssig[c], acc);
            acc = fmaf(W_ps[o*128 + 64 + c], b_tsig[c], acc);
        }
        wsf[WS_B0 + o] = acc * sps + be_ps[o];
        const float sraw = g_raw[o] / sqrtf(v_raw[o] + EPSF);
        wsf[WS_BC + o] = (b_raw[o] - m_raw[o]) * sraw + be_raw[o];
        const float sfu = g_fu[o] / sqrtf(v_fu[o] + EPSF);
        wsf[WS_BF + o] = (b_fu[o] - m_fu[o]) * sfu + be_fu[o];
        // conv weights in [i][o] layout (uniform s_loads either way)
        for (int i = 0; i < 9; ++i) wsf[WS_WC + i*64 + o] = W_raw[o*9 + i] * sraw;
    }
}

// FACTORED depth-3 signature step (round-9 lesson: no packed-fp32 on gfx950 --
// cut real FMA count instead). sig = [S1(0..3)|S2(4..19)|S3(20..83)], static-indexed.
//   S3[ijk] += (S2old[ij] + fv_i*dh_j) * d_k     (h: 16 fma, S3: 64 fma)
//   S2[ij]   = fma(S1_i + dh_i, d_j, S2[ij])     (q: 4 add, S2: 16 fma)
//   fv_i = S1_i + d_i/3 ; dh_i = 0.5*d_i ; S1 += d
// 112 inst/step vs 188 unfactored. Same math, regrouped rounding (ok vs threshold).
__device__ __forceinline__ void sig_step(float* __restrict__ sig, const float d[4])
{
    float* S1 = sig; float* S2 = sig + 4; float* S3 = sig + 20;
    float dh[4], fv[4];
#pragma unroll
    for (int i = 0; i < 4; ++i) dh[i] = 0.5f * d[i];
#pragma unroll
    for (int i = 0; i < 4; ++i) fv[i] = fmaf(d[i], (1.f/3.f), S1[i]);
    float h[16];
#pragma unroll
    for (int i = 0; i < 4; ++i)
#pragma unroll
        for (int j = 0; j < 4; ++j) h[i*4+j] = fmaf(fv[i], dh[j], S2[i*4+j]);  // OLD S2
#pragma unroll
    for (int i = 0; i < 4; ++i)
#pragma unroll
        for (int j = 0; j < 4; ++j) {
            const float hij = h[i*4+j];
#pragma unroll
            for (int k = 0; k < 4; ++k)
                S3[(i*4+j)*4+k] = fmaf(hij, d[k], S3[(i*4+j)*4+k]);
        }
    float q[4];
#pragma unroll
    for (int i = 0; i < 4; ++i) q[i] = S1[i] + dh[i];
#pragma unroll
    for (int i = 0; i < 4; ++i)
#pragma unroll
        for (int j = 0; j < 4; ++j) S2[i*4+j] = fmaf(q[i], d[j], S2[i*4+j]);
#pragma unroll
    for (int i = 0; i < 4; ++i) S1[i] += d[i];
}

// first step from zero state with d[3]==0: S1=d, S2=dh_i*d_j, S3=(d_i/3)*S2[jk]
__device__ __forceinline__ void sig_init(float* __restrict__ sig, float d0, float d1, float d2)
{
    const float dd[4] = { d0, d1, d2, 0.f };
#pragma unroll
    for (int i = 0; i < 4; ++i) sig[i] = dd[i];
#pragma unroll
    for (int i = 0; i < 4; ++i) {
        const float dh = 0.5f * dd[i];
#pragma unroll
        for (int j = 0; j < 4; ++j) sig[4 + i*4 + j] = dh * dd[j];
    }
#pragma unroll
    for (int i = 0; i < 4; ++i) {
        const float di3 = dd[i] * (1.f/3.f);
#pragma unroll
        for (int j = 0; j < 4; ++j)
#pragma unroll
            for (int k = 0; k < 4; ++k)
                sig[20 + (i*4+j)*4 + k] = di3 * sig[4 + j*4 + k];
    }
}

// grid: (4 t-chunks, 64 j, 32 b); block 64 = 1 wave; block owns t-cols [bx*64, bx*64+64).
// k-major LDS: slot s (16B per row) at byte s*1024 + row*16; 12 slots = 12288 B.
// PHASE ORDER avoids sig[84](f32) x acc(64 AGPR) live overlap (round-7 spill):
//   sigma_s -> LDS; sigma_t -> 42 packed u32 REGS; GEMM1a; dump sigma_t -> LDS; GEMM1b.
// Explicit __syncthreads() at every LDS W->R / R->W boundary (round-4 lesson).
__global__ __launch_bounds__(64, 3) void stem_main(
    const float* __restrict__ x, const int* __restrict__ path,
    const float* __restrict__ wsf, const unsigned short* __restrict__ wsA1,
    const unsigned short* __restrict__ wsA2, float* __restrict__ out)
{
    __shared__ char sb[12 * 1024];
    const int l  = threadIdx.x;                  // lane
    const int t  = blockIdx.x * 64 + l;          // global t for this thread's column
    const int j  = blockIdx.y;
    const int b  = blockIdx.z;
    const float* xb = x + (size_t)b * (3*64*256);

    const int lg = l >> 4;      // lane k-group
    const int li = l & 15;      // m/n index within tile
    char* const myw = sb + l*16;                 // write base: slot via immediate

    // ---- sigma_s: step-1 specialized, then 4 general steps (d3 = 0.25 literal) ----
    float sig[84];
    {
        int jp = path[j*5 + 0];
        float pr0 = xb[(0*64 + jp)*256 + t];
        float pr1 = xb[(1*64 + jp)*256 + t];
        float pr2 = xb[(2*64 + jp)*256 + t];
        sig_init(sig, pr0, pr1, pr2);
#pragma unroll
        for (int s = 1; s < 5; ++s) {
            jp = path[j*5 + s];
            const float p0 = xb[(0*64 + jp)*256 + t];
            const float p1 = xb[(1*64 + jp)*256 + t];
            const float p2 = xb[(2*64 + jp)*256 + t];
            const float d[4] = { p0-pr0, p1-pr1, p2-pr2, 0.25f };
            pr0=p0; pr1=p1; pr2=p2;
            sig_step(sig, d);
        }
    }
    // pack sigma_s k-major to LDS: slot v holds sig[8v..8v+7] (bf16), rows = lanes
    {
        unsigned uu[48];
#pragma unroll
        for (int i = 0; i < 42; ++i) uu[i] = cvtpk(sig[2*i], sig[2*i+1]);
#pragma unroll
        for (int i = 42; i < 48; ++i) uu[i] = 0u;
#pragma unroll
        for (int v = 0; v < 12; ++v) {
            uint32x4 w = { uu[4*v], uu[4*v+1], uu[4*v+2], uu[4*v+3] };
            *(uint32x4*)(myw + v*1024) = w;
        }
    }
    __syncthreads();                                      // W->R: sigma_s ready

    // ---- sigma_t NOW (before acc is born): scrambled window; result packed to regs ----
    unsigned uuT[48];
    {
        int idx  = j*7;
        int jsrc = idx & 63, tl = idx >> 6;
        int ts   = min(max(t + tl - 3, 0), 255);
        float pr0 = xb[(0*64 + jsrc)*256 + ts];
        float pr1 = xb[(1*64 + jsrc)*256 + ts];
        float pr2 = xb[(2*64 + jsrc)*256 + ts];
        sig_init(sig, pr0, pr1, pr2);
#pragma unroll
        for (int k = 1; k < 7; ++k) {
            idx = j*7 + k; jsrc = idx & 63; tl = idx >> 6;
            ts = min(max(t + tl - 3, 0), 255);
            const float p0 = xb[(0*64 + jsrc)*256 + ts];
            const float p1 = xb[(1*64 + jsrc)*256 + ts];
            const float p2 = xb[(2*64 + jsrc)*256 + ts];
            const float d[4] = { p0-pr0, p1-pr1, p2-pr2, (1.f/6.f) };
            pr0=p0; pr1=p1; pr2=p2;
            sig_step(sig, d);
        }
#pragma unroll
        for (int i = 0; i < 42; ++i) uuT[i] = cvtpk(sig[2*i], sig[2*i+1]);
#pragma unroll
        for (int i = 42; i < 48; ++i) uuT[i] = 0u;
    }
    // sig (f32) is DEAD here -> acc can use the freed registers

    // ---- GEMM1a: acc = B0 + A(h=0) * sigma_s ----
    f32x4 acc[4][4];
#pragma unroll
    for (int to = 0; to < 4; ++to) {
        const f32x4 b0 = *(const f32x4*)(wsf + WS_B0 + to*16 + lg*4);
#pragma unroll
        for (int tt = 0; tt < 4; ++tt) acc[to][tt] = b0;
    }
    {
#pragma unroll
        for (int s = 0; s < 3; ++s) {
            bf16x8 A0 = *(const bf16x8*)(wsA1 + ((0*3+s)*4+0)*512 + l*8);
            bf16x8 A1 = *(const bf16x8*)(wsA1 + ((0*3+s)*4+1)*512 + l*8);
            bf16x8 A2 = *(const bf16x8*)(wsA1 + ((0*3+s)*4+2)*512 + l*8);
            bf16x8 A3 = *(const bf16x8*)(wsA1 + ((0*3+s)*4+3)*512 + l*8);
#pragma unroll
            for (int tt = 0; tt < 4; ++tt) {
                const bf16x8 B = *(const bf16x8*)(sb + (s*4+lg)*1024 + (tt*16+li)*16);
                acc[0][tt] = __builtin_amdgcn_mfma_f32_16x16x32_bf16(A0, B, acc[0][tt], 0, 0, 0);
                acc[1][tt] = __builtin_amdgcn_mfma_f32_16x16x32_bf16(A1, B, acc[1][tt], 0, 0, 0);
                acc[2][tt] = __builtin_amdgcn_mfma_f32_16x16x32_bf16(A2, B, acc[2][tt], 0, 0, 0);
                acc[3][tt] = __builtin_amdgcn_mfma_f32_16x16x32_bf16(A3, B, acc[3][tt], 0, 0, 0);
            }
        }
    }
    __syncthreads();                                      // R->W: done reading sigma_s

    // dump packed sigma_t regs -> LDS
    {
#pragma unroll
        for (int v = 0; v < 12; ++v) {
            uint32x4 w = { uuT[4*v], uuT[4*v+1], uuT[4*v+2], uuT[4*v+3] };
            *(uint32x4*)(myw + v*1024) = w;
        }
    }
    __syncthreads();                                      // W->R: sigma_t ready

    // conv window loads issued here (HBM latency hides under GEMM1b + ps pack)
    float xv[9];
#pragma unroll
    for (int ci = 0; ci < 3; ++ci) {
        const float* xr = xb + (ci*64 + j)*256;
        xv[ci*3+0] = (t >= 1)   ? xr[t-1] : 0.f;
        xv[ci*3+1] = xr[t];
        xv[ci*3+2] = (t <= 254) ? xr[t+1] : 0.f;
    }

    // ---- GEMM1b: acc += A(h=1) * sigma_t ----
    {
#pragma unroll
        for (int s = 0; s < 3; ++s) {
            bf16x8 A0 = *(const bf16x8*)(wsA1 + ((1*3+s)*4+0)*512 + l*8);
            bf16x8 A1 = *(const bf16x8*)(wsA1 + ((1*3+s)*4+1)*512 + l*8);
            bf16x8 A2 = *(const bf16x8*)(wsA1 + ((1*3+s)*4+2)*512 + l*8);
            bf16x8 A3 = *(const bf16x8*)(wsA1 + ((1*3+s)*4+3)*512 + l*8);
#pragma unroll
            for (int tt = 0; tt < 4; ++tt) {
                const bf16x8 B = *(const bf16x8*)(sb + (s*4+lg)*1024 + (tt*16+li)*16);
                acc[0][tt] = __builtin_amdgcn_mfma_f32_16x16x32_bf16(A0, B, acc[0][tt], 0, 0, 0);
                acc[1][tt] = __builtin_amdgcn_mfma_f32_16x16x32_bf16(A1, B, acc[1][tt], 0, 0, 0);
                acc[2][tt] = __builtin_amdgcn_mfma_f32_16x16x32_bf16(A2, B, acc[2][tt], 0, 0, 0);
                acc[3][tt] = __builtin_amdgcn_mfma_f32_16x16x32_bf16(A3, B, acc[3][tt], 0, 0, 0);
            }
        }
    }
    __syncthreads();                                      // R->W: done reading sigma_t

    // ---- ps pack: u_ps[row][o] = bf16(relu(acc)), k-major (slot = o>>3) ----
#pragma unroll
    for (int to = 0; to < 4; ++to) {
#pragma unroll
        for (int tt = 0; tt < 4; ++tt) {
            const unsigned w0 = cvtpk(fmaxf(acc[to][tt][0], 0.f), fmaxf(acc[to][tt][1], 0.f));
            const unsigned w1 = cvtpk(fmaxf(acc[to][tt][2], 0.f), fmaxf(acc[to][tt][3], 0.f));
            uint32x2 w = { w0, w1 };
            *(uint32x2*)(sb + (to*2+(lg>>1))*1024 + (tt*16+li)*16 + ((lg&1)<<3)) = w;
        }
    }

    // ---- conv into cu regs (scalar fma; VALU; no LDS) while ps stores land ----
    unsigned cu[32];
#pragma unroll
    for (int cc = 0; cc < 32; ++cc) {
        float v0 = wsf[WS_BC + 2*cc];
        float v1 = wsf[WS_BC + 2*cc + 1];
#pragma unroll
        for (int i = 0; i < 9; ++i) {
            v0 = fmaf(xv[i], wsf[WS_WC + i*64 + 2*cc],     v0);
            v1 = fmaf(xv[i], wsf[WS_WC + i*64 + 2*cc + 1], v1);
        }
        cu[cc] = cvtpk(fmaxf(v0, 0.f), fmaxf(v1, 0.f));
    }
    __syncthreads();                                      // W->R: u_ps ready

    // ---- GEMM2-ps: acc = BF + Wf_hi^T u_ps  (A2 frags q = 8..15) ----
#pragma unroll
    for (int to = 0; to < 4; ++to) {
        const f32x4 bf4 = *(const f32x4*)(wsf + WS_BF + to*16 + lg*4);
#pragma unroll
        for (int tt = 0; tt < 4; ++tt) acc[to][tt] = bf4;
    }
    {
#pragma unroll
        for (int s = 0; s < 2; ++s) {
            bf16x8 A0 = *(const bf16x8*)(wsA2 + ((s+2)*4+0)*512 + l*8);
            bf16x8 A1 = *(const bf16x8*)(wsA2 + ((s+2)*4+1)*512 + l*8);
            bf16x8 A2 = *(const bf16x8*)(wsA2 + ((s+2)*4+2)*512 + l*8);
            bf16x8 A3 = *(const bf16x8*)(wsA2 + ((s+2)*4+3)*512 + l*8);
#pragma unroll
            for (int tt = 0; tt < 4; ++tt) {
                const bf16x8 B = *(const bf16x8*)(sb + (s*4+lg)*1024 + (tt*16+li)*16);
                acc[0][tt] = __builtin_amdgcn_mfma_f32_16x16x32_bf16(A0, B, acc[0][tt], 0, 0, 0);
                acc[1][tt] = __builtin_amdgcn_mfma_f32_16x16x32_bf16(A1, B, acc[1][tt], 0, 0, 0);
                acc[2][tt] = __builtin_amdgcn_mfma_f32_16x16x32_bf16(A2, B, acc[2][tt], 0, 0, 0);
                acc[3][tt] = __builtin_amdgcn_mfma_f32_16x16x32_bf16(A3, B, acc[3][tt], 0, 0, 0);
            }
        }
    }
    __syncthreads();                                      // R->W: done reading u_ps

    // ---- conv store: u_conv[row][c], own row, k-major ----
    {
#pragma unroll
        for (int v = 0; v < 8; ++v) {
            uint32x4 w = { cu[4*v], cu[4*v+1], cu[4*v+2], cu[4*v+3] };
            *(uint32x4*)(myw + v*1024) = w;
        }
    }
    __syncthreads();                                      // W->R: u_conv ready

    // ---- GEMM2-conv: acc += Wf_lo^T u_conv  (A2 frags q = 0..7) ----
    {
#pragma unroll
        for (int s = 0; s < 2; ++s) {
            bf16x8 A0 = *(const bf16x8*)(wsA2 + (s*4+0)*512 + l*8);
            bf16x8 A1 = *(const bf16x8*)(wsA2 + (s*4+1)*512 + l*8);
            bf16x8 A2 = *(const bf16x8*)(wsA2 + (s*4+2)*512 + l*8);
            bf16x8 A3 = *(const bf16x8*)(wsA2 + (s*4+3)*512 + l*8);
#pragma unroll
            for (int tt = 0; tt < 4; ++tt) {
                const bf16x8 B = *(const bf16x8*)(sb + (s*4+lg)*1024 + (tt*16+li)*16);
                acc[0][tt] = __builtin_amdgcn_mfma_f32_16x16x32_bf16(A0, B, acc[0][tt], 0, 0, 0);
                acc[1][tt] = __builtin_amdgcn_mfma_f32_16x16x32_bf16(A1, B, acc[1][tt], 0, 0, 0);
                acc[2][tt] = __builtin_amdgcn_mfma_f32_16x16x32_bf16(A2, B, acc[2][tt], 0, 0, 0);
                acc[3][tt] = __builtin_amdgcn_mfma_f32_16x16x32_bf16(A3, B, acc[3][tt], 0, 0, 0);
            }
        }
    }

    // ---- final epilogue: relu (bias already in C-init), store out[b][o][j][t] ----
#pragma unroll
    for (int to = 0; to < 4; ++to) {
#pragma unroll
        for (int tt = 0; tt < 4; ++tt) {
            const int tg = blockIdx.x*64 + tt*16 + li;
#pragma unroll
            for (int r = 0; r < 4; ++r) {
                const int o = to*16 + lg*4 + r;
                out[(((size_t)b*64 + o)*64 + j)*256 + tg] = fmaxf(acc[to][tt][r], 0.f);
            }
        }
    }
}

extern "C" void kernel_launch(void* const* d_in, const int* in_sizes, int n_in,
                              void* d_out, int out_size, void* d_ws, size_t ws_size,
                              hipStream_t stream)
{
    const float* x      = (const float*)d_in[0];
    const int*   path   = (const int*)  d_in[1];
    const float* W_ssig = (const float*)d_in[2];
    const float* b_ssig = (const float*)d_in[3];
    const float* W_tsig = (const float*)d_in[4];
    const float* b_tsig = (const float*)d_in[5];
    const float* W_raw  = (const float*)d_in[6];
    const float* b_raw  = (const float*)d_in[7];
    const float* W_ps   = (const float*)d_in[8];
    const float* b_ps   = (const float*)d_in[9];
    const float* W_fu   = (const float*)d_in[10];
    const float* b_fu   = (const float*)d_in[11];
    const float* g_raw  = (const float*)d_in[12];
    const float* be_raw = (const float*)d_in[13];
    const float* m_raw  = (const float*)d_in[14];
    const float* v_raw  = (const float*)d_in[15];
    const float* g_ps   = (const float*)d_in[16];
    const float* be_ps  = (const float*)d_in[17];
    const float* m_ps   = (const float*)d_in[18];
    const float* v_ps   = (const float*)d_in[19];
    const float* g_fu   = (const float*)d_in[20];
    const float* be_fu  = (const float*)d_in[21];
    const float* m_fu   = (const float*)d_in[22];
    const float* v_fu   = (const float*)d_in[23];
    float* out = (float*)d_out;

    float*          wsf  = (float*)d_ws;
    unsigned short* wsA1 = (unsigned short*)((char*)d_ws + 4096);
    unsigned short* wsA2 = (unsigned short*)((char*)d_ws + 28672);

    stem_prep<<<41, 64, 0, stream>>>(W_ssig, b_ssig, W_tsig, b_tsig, W_raw, b_raw,
                                     W_ps, b_ps, W_fu, b_fu,
                                     g_raw, be_raw, m_raw, v_raw,
                                     g_ps, be_ps, m_ps, v_ps,
                                     g_fu, be_fu, m_fu, v_fu, wsf, wsA1, wsA2);

    dim3 grid(4, 64, 32);   // (t-chunks, J, B)
    stem_main<<<grid, 64, 0, stream>>>(x, path, wsf, wsA1, wsA2, out);
}

// Round 11
// 65.105 us; speedup vs baseline: 1.3004x; 1.0582x over previous
//
#include <hip/hip_runtime.h>
#include <cstdint>

#define EPSF 1e-5f

typedef __attribute__((ext_vector_type(8))) short     bf16x8;
typedef __attribute__((ext_vector_type(4))) float     f32x4;
typedef __attribute__((ext_vector_type(4))) unsigned int uint32x4;
typedef __attribute__((ext_vector_type(2))) unsigned int uint32x2;

// ---- workspace layout ----
// floats (at byte 0): B0[64] @0, BC[64] @64, BF[64] @128
#define WS_B0 0
#define WS_BC 64
#define WS_BF 128
// bf16 A-fragments: wsA1 at byte 4096  (24 frags * 512 = 12288 ushort)
//                   wsA2 at byte 28672 (16 frags * 512 =  8192 ushort)
//                   wsA3 at byte 45056 ( 4 frags * 512 =  2048 ushort)  conv K=32(pad from 9)

__device__ __forceinline__ unsigned short f2bf(float f) {
    union { float f; unsigned u; } v; v.f = f;
    unsigned r = v.u + 0x7fffu + ((v.u >> 16) & 1u);   // RNE
    return (unsigned short)(r >> 16);
}

// packed f32x2 -> bf16x2 (RNE), single HW instruction on gfx950
__device__ __forceinline__ unsigned cvtpk(float lo, float hi) {
    unsigned r;
    asm("v_cvt_pk_bf16_f32 %0, %1, %2" : "=v"(r) : "v"(lo), "v"(hi));
    return r;
}

// ---------------- prep: fold BNs, collapse W_ps@{W_ssig,W_tsig}, pack MFMA A-frags ----------------
__global__ __launch_bounds__(64) void stem_prep(
    const float* __restrict__ W_ssig, const float* __restrict__ b_ssig,
    const float* __restrict__ W_tsig, const float* __restrict__ b_tsig,
    const float* __restrict__ W_raw,  const float* __restrict__ b_raw,
    const float* __restrict__ W_ps,   const float* __restrict__ b_ps,
    const float* __restrict__ W_fu,   const float* __restrict__ b_fu,
    const float* __restrict__ g_raw, const float* __restrict__ be_raw,
    const float* __restrict__ m_raw, const float* __restrict__ v_raw,
    const float* __restrict__ g_ps,  const float* __restrict__ be_ps,
    const float* __restrict__ m_ps,  const float* __restrict__ v_ps,
    const float* __restrict__ g_fu,  const float* __restrict__ be_fu,
    const float* __restrict__ m_fu,  const float* __restrict__ v_fu,
    float* __restrict__ wsf, unsigned short* __restrict__ wsA1,
    unsigned short* __restrict__ wsA2, unsigned short* __restrict__ wsA3)
{
    const int l = threadIdx.x;         // 0..63
    const int f = blockIdx.x;
    if (f < 24) {
        // A1 frag f = h*12 + s*4 + to ; element b: W1[k=s*32+8*(l>>4)+b][o=to*16+(l&15)]
        const int h = f / 12, rem = f % 12, s = rem / 4, to = rem % 4;
        const int o = to*16 + (l & 15);
        const float sps = g_ps[o] / sqrtf(v_ps[o] + EPSF);
        const float* wp  = W_ps + o*128 + 64*h;
        const float* wsg = h ? W_tsig : W_ssig;
        for (int b = 0; b < 8; ++b) {
            const int k = s*32 + ((l >> 4) * 8) + b;
            float v = 0.f;
            if (k < 84) {
                float acc = 0.f;
                for (int c = 0; c < 64; ++c) acc = fmaf(wp[c], wsg[c*84 + k], acc);
                v = acc * sps;
            }
            wsA1[f*512 + l*8 + b] = f2bf(v);
        }
    } else if (f < 40) {
        // A2 frag q = s*4+to ; element b: Wf[c=s*32+8*(l>>4)+b][o] = sfu[o]*W_fu[o*128+c]
        const int q = f - 24, s = q / 4, to = q % 4;
        const int o = to*16 + (l & 15);
        const float sfu = g_fu[o] / sqrtf(v_fu[o] + EPSF);
        for (int b = 0; b < 8; ++b) {
            const int c = s*32 + ((l >> 4) * 8) + b;
            wsA2[q*512 + l*8 + b] = f2bf(W_fu[o*128 + c] * sfu);
        }
    } else if (f == 40) {
        const int o = l;
        const float sps = g_ps[o] / sqrtf(v_ps[o] + EPSF);
        float acc = b_ps[o] - m_ps[o];
        for (int c = 0; c < 64; ++c) {
            acc = fmaf(W_ps[o*128 + c],      b_ssig[c], acc);
            acc = fmaf(W_ps[o*128 + 64 + c], b_tsig[c], acc);
        }
        wsf[WS_B0 + o] = acc * sps + be_ps[o];
        const float sraw = g_raw[o] / sqrtf(v_raw[o] + EPSF);
        wsf[WS_BC + o] = (b_raw[o] - m_raw[o]) * sraw + be_raw[o];
        const float sfu = g_fu[o] / sqrtf(v_fu[o] + EPSF);
        wsf[WS_BF + o] = (b_fu[o] - m_fu[o]) * sfu + be_fu[o];
    } else {
        // A3 frag to = f-41 ; element b: k = 8*(l>>4)+b; Wc[k][o] = sraw[o]*W_raw[o*9+k] (k<9)
        const int to = f - 41;
        const int o = to*16 + (l & 15);
        const float sraw = g_raw[o] / sqrtf(v_raw[o] + EPSF);
        for (int b = 0; b < 8; ++b) {
            const int k = ((l >> 4) * 8) + b;
            wsA3[to*512 + l*8 + b] = (k < 9) ? f2bf(W_raw[o*9 + k] * sraw) : (unsigned short)0;
        }
    }
}

// FACTORED depth-3 signature step. sig = [S1(0..3)|S2(4..19)|S3(20..83)], static-indexed.
//   S3[ijk] += (S2old[ij] + fv_i*dh_j) * d_k ; S2[ij] = fma(S1_i+dh_i, d_j, S2[ij])
//   fv_i = S1_i + d_i/3 ; dh_i = 0.5*d_i ; S1 += d        (112 inst/step)
__device__ __forceinline__ void sig_step(float* __restrict__ sig, const float d[4])
{
    float* S1 = sig; float* S2 = sig + 4; float* S3 = sig + 20;
    float dh[4], fv[4];
#pragma unroll
    for (int i = 0; i < 4; ++i) dh[i] = 0.5f * d[i];
#pragma unroll
    for (int i = 0; i < 4; ++i) fv[i] = fmaf(d[i], (1.f/3.f), S1[i]);
    float h[16];
#pragma unroll
    for (int i = 0; i < 4; ++i)
#pragma unroll
        for (int j = 0; j < 4; ++j) h[i*4+j] = fmaf(fv[i], dh[j], S2[i*4+j]);  // OLD S2
#pragma unroll
    for (int i = 0; i < 4; ++i)
#pragma unroll
        for (int j = 0; j < 4; ++j) {
            const float hij = h[i*4+j];
#pragma unroll
            for (int k = 0; k < 4; ++k)
                S3[(i*4+j)*4+k] = fmaf(hij, d[k], S3[(i*4+j)*4+k]);
        }
    float q[4];
#pragma unroll
    for (int i = 0; i < 4; ++i) q[i] = S1[i] + dh[i];
#pragma unroll
    for (int i = 0; i < 4; ++i)
#pragma unroll
        for (int j = 0; j < 4; ++j) S2[i*4+j] = fmaf(q[i], d[j], S2[i*4+j]);
#pragma unroll
    for (int i = 0; i < 4; ++i) S1[i] += d[i];
}

// first step from zero state with d[3]==0: S1=d, S2=dh_i*d_j, S3=(d_i/3)*S2[jk]
__device__ __forceinline__ void sig_init(float* __restrict__ sig, float d0, float d1, float d2)
{
    const float dd[4] = { d0, d1, d2, 0.f };
#pragma unroll
    for (int i = 0; i < 4; ++i) sig[i] = dd[i];
#pragma unroll
    for (int i = 0; i < 4; ++i) {
        const float dh = 0.5f * dd[i];
#pragma unroll
        for (int j = 0; j < 4; ++j) sig[4 + i*4 + j] = dh * dd[j];
    }
#pragma unroll
    for (int i = 0; i < 4; ++i) {
        const float di3 = dd[i] * (1.f/3.f);
#pragma unroll
        for (int j = 0; j < 4; ++j)
#pragma unroll
            for (int k = 0; k < 4; ++k)
                sig[20 + (i*4+j)*4 + k] = di3 * sig[4 + j*4 + k];
    }
}

// grid: (4 t-chunks, 64 j, 32 b); block 64 = 1 wave; block owns t-cols [bx*64, bx*64+64).
// k-major LDS: slot s (16B per row) at byte s*1024 + row*16; 12 slots = 12288 B.
// conv computed via MFMA (K=9 padded to 32; xv in slots 8..11, bf16).
// Explicit __syncthreads() at every LDS W->R / R->W boundary (round-4 lesson).
__global__ __launch_bounds__(64, 3) void stem_main(
    const float* __restrict__ x, const int* __restrict__ path,
    const float* __restrict__ wsf, const unsigned short* __restrict__ wsA1,
    const unsigned short* __restrict__ wsA2, const unsigned short* __restrict__ wsA3,
    float* __restrict__ out)
{
    __shared__ char sb[12 * 1024];
    const int l  = threadIdx.x;                  // lane
    const int t  = blockIdx.x * 64 + l;          // global t for this thread's column
    const int j  = blockIdx.y;
    const int b  = blockIdx.z;
    const float* xb = x + (size_t)b * (3*64*256);

    const int lg = l >> 4;      // lane k-group
    const int li = l & 15;      // m/n index within tile
    char* const myw = sb + l*16;                 // write base: slot via immediate

    // ---- sigma_s: step-1 specialized, then 4 general steps (d3 = 0.25 literal) ----
    float sig[84];
    {
        int jp = path[j*5 + 0];
        float pr0 = xb[(0*64 + jp)*256 + t];
        float pr1 = xb[(1*64 + jp)*256 + t];
        float pr2 = xb[(2*64 + jp)*256 + t];
        sig_init(sig, pr0, pr1, pr2);
#pragma unroll
        for (int s = 1; s < 5; ++s) {
            jp = path[j*5 + s];
            const float p0 = xb[(0*64 + jp)*256 + t];
            const float p1 = xb[(1*64 + jp)*256 + t];
            const float p2 = xb[(2*64 + jp)*256 + t];
            const float d[4] = { p0-pr0, p1-pr1, p2-pr2, 0.25f };
            pr0=p0; pr1=p1; pr2=p2;
            sig_step(sig, d);
        }
    }
    // pack sigma_s k-major to LDS: slot v holds sig[8v..8v+7] (bf16), rows = lanes
    {
        unsigned uu[48];
#pragma unroll
        for (int i = 0; i < 42; ++i) uu[i] = cvtpk(sig[2*i], sig[2*i+1]);
#pragma unroll
        for (int i = 42; i < 48; ++i) uu[i] = 0u;
#pragma unroll
        for (int v = 0; v < 12; ++v) {
            uint32x4 w = { uu[4*v], uu[4*v+1], uu[4*v+2], uu[4*v+3] };
            *(uint32x4*)(myw + v*1024) = w;
        }
    }
    __syncthreads();                                      // W->R: sigma_s ready

    // ---- sigma_t NOW (before acc is born): scrambled window; result packed to regs ----
    unsigned uuT[48];
    {
        int idx  = j*7;
        int jsrc = idx & 63, tl = idx >> 6;
        int ts   = min(max(t + tl - 3, 0), 255);
        float pr0 = xb[(0*64 + jsrc)*256 + ts];
        float pr1 = xb[(1*64 + jsrc)*256 + ts];
        float pr2 = xb[(2*64 + jsrc)*256 + ts];
        sig_init(sig, pr0, pr1, pr2);
#pragma unroll
        for (int k = 1; k < 7; ++k) {
            idx = j*7 + k; jsrc = idx & 63; tl = idx >> 6;
            ts = min(max(t + tl - 3, 0), 255);
            const float p0 = xb[(0*64 + jsrc)*256 + ts];
            const float p1 = xb[(1*64 + jsrc)*256 + ts];
            const float p2 = xb[(2*64 + jsrc)*256 + ts];
            const float d[4] = { p0-pr0, p1-pr1, p2-pr2, (1.f/6.f) };
            pr0=p0; pr1=p1; pr2=p2;
            sig_step(sig, d);
        }
#pragma unroll
        for (int i = 0; i < 42; ++i) uuT[i] = cvtpk(sig[2*i], sig[2*i+1]);
#pragma unroll
        for (int i = 42; i < 48; ++i) uuT[i] = 0u;
    }
    // sig (f32) is DEAD here -> acc can use the freed registers

    // ---- GEMM1a: acc = B0 + A(h=0) * sigma_s ----
    f32x4 acc[4][4];
#pragma unroll
    for (int to = 0; to < 4; ++to) {
        const f32x4 b0 = *(const f32x4*)(wsf + WS_B0 + to*16 + lg*4);
#pragma unroll
        for (int tt = 0; tt < 4; ++tt) acc[to][tt] = b0;
    }
    {
#pragma unroll
        for (int s = 0; s < 3; ++s) {
            bf16x8 A0 = *(const bf16x8*)(wsA1 + ((0*3+s)*4+0)*512 + l*8);
            bf16x8 A1 = *(const bf16x8*)(wsA1 + ((0*3+s)*4+1)*512 + l*8);
            bf16x8 A2 = *(const bf16x8*)(wsA1 + ((0*3+s)*4+2)*512 + l*8);
            bf16x8 A3 = *(const bf16x8*)(wsA1 + ((0*3+s)*4+3)*512 + l*8);
#pragma unroll
            for (int tt = 0; tt < 4; ++tt) {
                const bf16x8 B = *(const bf16x8*)(sb + (s*4+lg)*1024 + (tt*16+li)*16);
                acc[0][tt] = __builtin_amdgcn_mfma_f32_16x16x32_bf16(A0, B, acc[0][tt], 0, 0, 0);
                acc[1][tt] = __builtin_amdgcn_mfma_f32_16x16x32_bf16(A1, B, acc[1][tt], 0, 0, 0);
                acc[2][tt] = __builtin_amdgcn_mfma_f32_16x16x32_bf16(A2, B, acc[2][tt], 0, 0, 0);
                acc[3][tt] = __builtin_amdgcn_mfma_f32_16x16x32_bf16(A3, B, acc[3][tt], 0, 0, 0);
            }
        }
    }
    __syncthreads();                                      // R->W: done reading sigma_s

    // dump packed sigma_t regs -> LDS
    {
#pragma unroll
        for (int v = 0; v < 12; ++v) {
            uint32x4 w = { uuT[4*v], uuT[4*v+1], uuT[4*v+2], uuT[4*v+3] };
            *(uint32x4*)(myw + v*1024) = w;
        }
    }
    __syncthreads();                                      // W->R: sigma_t ready

    // conv window loads issued here (HBM latency hides under GEMM1b)
    float xv[9];
#pragma unroll
    for (int ci = 0; ci < 3; ++ci) {
        const float* xr = xb + (ci*64 + j)*256;
        xv[ci*3+0] = (t >= 1)   ? xr[t-1] : 0.f;
        xv[ci*3+1] = xr[t];
        xv[ci*3+2] = (t <= 254) ? xr[t+1] : 0.f;
    }

    // ---- GEMM1b: acc += A(h=1) * sigma_t ----
    {
#pragma unroll
        for (int s = 0; s < 3; ++s) {
            bf16x8 A0 = *(const bf16x8*)(wsA1 + ((1*3+s)*4+0)*512 + l*8);
            bf16x8 A1 = *(const bf16x8*)(wsA1 + ((1*3+s)*4+1)*512 + l*8);
            bf16x8 A2 = *(const bf16x8*)(wsA1 + ((1*3+s)*4+2)*512 + l*8);
            bf16x8 A3 = *(const bf16x8*)(wsA1 + ((1*3+s)*4+3)*512 + l*8);
#pragma unroll
            for (int tt = 0; tt < 4; ++tt) {
                const bf16x8 B = *(const bf16x8*)(sb + (s*4+lg)*1024 + (tt*16+li)*16);
                acc[0][tt] = __builtin_amdgcn_mfma_f32_16x16x32_bf16(A0, B, acc[0][tt], 0, 0, 0);
                acc[1][tt] = __builtin_amdgcn_mfma_f32_16x16x32_bf16(A1, B, acc[1][tt], 0, 0, 0);
                acc[2][tt] = __builtin_amdgcn_mfma_f32_16x16x32_bf16(A2, B, acc[2][tt], 0, 0, 0);
                acc[3][tt] = __builtin_amdgcn_mfma_f32_16x16x32_bf16(A3, B, acc[3][tt], 0, 0, 0);
            }
        }
    }
    __syncthreads();                                      // R->W: done reading sigma_t

    // ---- ps pack: u_ps[row][o] = bf16(relu(acc)), k-major slots 0..7 (slot = o>>3) ----
#pragma unroll
    for (int to = 0; to < 4; ++to) {
#pragma unroll
        for (int tt = 0; tt < 4; ++tt) {
            const unsigned w0 = cvtpk(fmaxf(acc[to][tt][0], 0.f), fmaxf(acc[to][tt][1], 0.f));
            const unsigned w1 = cvtpk(fmaxf(acc[to][tt][2], 0.f), fmaxf(acc[to][tt][3], 0.f));
            uint32x2 w = { w0, w1 };
            *(uint32x2*)(sb + (to*2+(lg>>1))*1024 + (tt*16+li)*16 + ((lg&1)<<3)) = w;
        }
    }
    // ---- xv pack (bf16) -> slots 8..11 (K=32, zeros beyond k=8) ----
    {
        unsigned xu[16];
        xu[0] = cvtpk(xv[0], xv[1]); xu[1] = cvtpk(xv[2], xv[3]);
        xu[2] = cvtpk(xv[4], xv[5]); xu[3] = cvtpk(xv[6], xv[7]);
        xu[4] = cvtpk(xv[8], 0.f);
#pragma unroll
        for (int i = 5; i < 16; ++i) xu[i] = 0u;
#pragma unroll
        for (int v = 0; v < 4; ++v) {
            uint32x4 w = { xu[4*v], xu[4*v+1], xu[4*v+2], xu[4*v+3] };
            *(uint32x4*)(myw + (8+v)*1024) = w;
        }
    }
    __syncthreads();                                      // W->R: u_ps + xv ready

    // ---- GEMM-conv via MFMA: acc = BC + Wc * xv  (K=32, slots 8..11, A3 frags) ----
#pragma unroll
    for (int to = 0; to < 4; ++to) {
        const f32x4 bc4 = *(const f32x4*)(wsf + WS_BC + to*16 + lg*4);
#pragma unroll
        for (int tt = 0; tt < 4; ++tt) acc[to][tt] = bc4;
    }
    {
        bf16x8 A0 = *(const bf16x8*)(wsA3 + 0*512 + l*8);
        bf16x8 A1 = *(const bf16x8*)(wsA3 + 1*512 + l*8);
        bf16x8 A2 = *(const bf16x8*)(wsA3 + 2*512 + l*8);
        bf16x8 A3 = *(const bf16x8*)(wsA3 + 3*512 + l*8);
#pragma unroll
        for (int tt = 0; tt < 4; ++tt) {
            const bf16x8 B = *(const bf16x8*)(sb + (8+lg)*1024 + (tt*16+li)*16);
            acc[0][tt] = __builtin_amdgcn_mfma_f32_16x16x32_bf16(A0, B, acc[0][tt], 0, 0, 0);
            acc[1][tt] = __builtin_amdgcn_mfma_f32_16x16x32_bf16(A1, B, acc[1][tt], 0, 0, 0);
            acc[2][tt] = __builtin_amdgcn_mfma_f32_16x16x32_bf16(A2, B, acc[2][tt], 0, 0, 0);
            acc[3][tt] = __builtin_amdgcn_mfma_f32_16x16x32_bf16(A3, B, acc[3][tt], 0, 0, 0);
        }
    }
    // relu-pack conv result to regs (same [row][o] mapping as ps pack, held in cu)
    unsigned cu[32];
#pragma unroll
    for (int to = 0; to < 4; ++to)
#pragma unroll
        for (int tt = 0; tt < 4; ++tt) {
            cu[(to*4+tt)*2+0] = cvtpk(fmaxf(acc[to][tt][0], 0.f), fmaxf(acc[to][tt][1], 0.f));
            cu[(to*4+tt)*2+1] = cvtpk(fmaxf(acc[to][tt][2], 0.f), fmaxf(acc[to][tt][3], 0.f));
        }

    // ---- GEMM2-ps: acc = BF + Wf_hi^T u_ps  (A2 frags q = 8..15, slots 0..7) ----
#pragma unroll
    for (int to = 0; to < 4; ++to) {
        const f32x4 bf4 = *(const f32x4*)(wsf + WS_BF + to*16 + lg*4);
#pragma unroll
        for (int tt = 0; tt < 4; ++tt) acc[to][tt] = bf4;
    }
    {
#pragma unroll
        for (int s = 0; s < 2; ++s) {
            bf16x8 A0 = *(const bf16x8*)(wsA2 + ((s+2)*4+0)*512 + l*8);
            bf16x8 A1 = *(const bf16x8*)(wsA2 + ((s+2)*4+1)*512 + l*8);
            bf16x8 A2 = *(const bf16x8*)(wsA2 + ((s+2)*4+2)*512 + l*8);
            bf16x8 A3 = *(const bf16x8*)(wsA2 + ((s+2)*4+3)*512 + l*8);
#pragma unroll
            for (int tt = 0; tt < 4; ++tt) {
                const bf16x8 B = *(const bf16x8*)(sb + (s*4+lg)*1024 + (tt*16+li)*16);
                acc[0][tt] = __builtin_amdgcn_mfma_f32_16x16x32_bf16(A0, B, acc[0][tt], 0, 0, 0);
                acc[1][tt] = __builtin_amdgcn_mfma_f32_16x16x32_bf16(A1, B, acc[1][tt], 0, 0, 0);
                acc[2][tt] = __builtin_amdgcn_mfma_f32_16x16x32_bf16(A2, B, acc[2][tt], 0, 0, 0);
                acc[3][tt] = __builtin_amdgcn_mfma_f32_16x16x32_bf16(A3, B, acc[3][tt], 0, 0, 0);
            }
        }
    }
    __syncthreads();                                      // R->W: done reading u_ps

    // ---- conv store: u_conv[row][o] from cu -> slots 0..7 (same map as ps pack) ----
#pragma unroll
    for (int to = 0; to < 4; ++to)
#pragma unroll
        for (int tt = 0; tt < 4; ++tt) {
            uint32x2 w = { cu[(to*4+tt)*2+0], cu[(to*4+tt)*2+1] };
            *(uint32x2*)(sb + (to*2+(lg>>1))*1024 + (tt*16+li)*16 + ((lg&1)<<3)) = w;
        }
    __syncthreads();                                      // W->R: u_conv ready

    // ---- GEMM2-conv: acc += Wf_lo^T u_conv  (A2 frags q = 0..7, slots 0..7) ----
    {
#pragma unroll
        for (int s = 0; s < 2; ++s) {
            bf16x8 A0 = *(const bf16x8*)(wsA2 + (s*4+0)*512 + l*8);
            bf16x8 A1 = *(const bf16x8*)(wsA2 + (s*4+1)*512 + l*8);
            bf16x8 A2 = *(const bf16x8*)(wsA2 + (s*4+2)*512 + l*8);
            bf16x8 A3 = *(const bf16x8*)(wsA2 + (s*4+3)*512 + l*8);
#pragma unroll
            for (int tt = 0; tt < 4; ++tt) {
                const bf16x8 B = *(const bf16x8*)(sb + (s*4+lg)*1024 + (tt*16+li)*16);
                acc[0][tt] = __builtin_amdgcn_mfma_f32_16x16x32_bf16(A0, B, acc[0][tt], 0, 0, 0);
                acc[1][tt] = __builtin_amdgcn_mfma_f32_16x16x32_bf16(A1, B, acc[1][tt], 0, 0, 0);
                acc[2][tt] = __builtin_amdgcn_mfma_f32_16x16x32_bf16(A2, B, acc[2][tt], 0, 0, 0);
                acc[3][tt] = __builtin_amdgcn_mfma_f32_16x16x32_bf16(A3, B, acc[3][tt], 0, 0, 0);
            }
        }
    }

    // ---- final epilogue: relu (bias already in C-init), store out[b][o][j][t] ----
#pragma unroll
    for (int to = 0; to < 4; ++to) {
#pragma unroll
        for (int tt = 0; tt < 4; ++tt) {
            const int tg = blockIdx.x*64 + tt*16 + li;
#pragma unroll
            for (int r = 0; r < 4; ++r) {
                const int o = to*16 + lg*4 + r;
                out[(((size_t)b*64 + o)*64 + j)*256 + tg] = fmaxf(acc[to][tt][r], 0.f);
            }
        }
    }
}

extern "C" void kernel_launch(void* const* d_in, const int* in_sizes, int n_in,
                              void* d_out, int out_size, void* d_ws, size_t ws_size,
                              hipStream_t stream)
{
    const float* x      = (const float*)d_in[0];
    const int*   path   = (const int*)  d_in[1];
    const float* W_ssig = (const float*)d_in[2];
    const float* b_ssig = (const float*)d_in[3];
    const float* W_tsig = (const float*)d_in[4];
    const float* b_tsig = (const float*)d_in[5];
    const float* W_raw  = (const float*)d_in[6];
    const float* b_raw  = (const float*)d_in[7];
    const float* W_ps   = (const float*)d_in[8];
    const float* b_ps   = (const float*)d_in[9];
    const float* W_fu   = (const float*)d_in[10];
    const float* b_fu   = (const float*)d_in[11];
    const float* g_raw  = (const float*)d_in[12];
    const float* be_raw = (const float*)d_in[13];
    const float* m_raw  = (const float*)d_in[14];
    const float* v_raw  = (const float*)d_in[15];
    const float* g_ps   = (const float*)d_in[16];
    const float* be_ps  = (const float*)d_in[17];
    const float* m_ps   = (const float*)d_in[18];
    const float* v_ps   = (const float*)d_in[19];
    const float* g_fu   = (const float*)d_in[20];
    const float* be_fu  = (const float*)d_in[21];
    const float* m_fu   = (const float*)d_in[22];
    const float* v_fu   = (const float*)d_in[23];
    float* out = (float*)d_out;

    float*          wsf  = (float*)d_ws;
    unsigned short* wsA1 = (unsigned short*)((char*)d_ws + 4096);
    unsigned short* wsA2 = (unsigned short*)((char*)d_ws + 28672);
    unsigned short* wsA3 = (unsigned short*)((char*)d_ws + 45056);

    stem_prep<<<45, 64, 0, stream>>>(W_ssig, b_ssig, W_tsig, b_tsig, W_raw, b_raw,
                                     W_ps, b_ps, W_fu, b_fu,
                                     g_raw, be_raw, m_raw, v_raw,
                                     g_ps, be_ps, m_ps, v_ps,
                                     g_fu, be_fu, m_fu, v_fu, wsf, wsA1, wsA2, wsA3);

    dim3 grid(4, 64, 32);   // (t-chunks, J, B)
    stem_main<<<grid, 64, 0, stream>>>(x, path, wsf, wsA1, wsA2, wsA3, out);
}

// Round 12
// 64.085 us; speedup vs baseline: 1.3211x; 1.0159x over previous
//
#include <hip/hip_runtime.h>
#include <cstdint>

#define EPSF 1e-5f

typedef __attribute__((ext_vector_type(8))) short     bf16x8;
typedef __attribute__((ext_vector_type(4))) float     f32x4;
typedef __attribute__((ext_vector_type(4))) unsigned int uint32x4;
typedef __attribute__((ext_vector_type(2))) unsigned int uint32x2;

// ---- workspace layout ----
// floats (at byte 0): B0[64] @0, BC[64] @64, BF[64] @128
#define WS_B0 0
#define WS_BC 64
#define WS_BF 128
// bf16 A-fragments: wsA1 at byte 4096  (24 frags * 512 = 12288 ushort)
//                   wsA2 at byte 28672 (16 frags * 512 =  8192 ushort)
//                   wsA3 at byte 45056 ( 4 frags * 512 =  2048 ushort)  conv K=32(pad from 9)

__device__ __forceinline__ unsigned short f2bf(float f) {
    union { float f; unsigned u; } v; v.f = f;
    unsigned r = v.u + 0x7fffu + ((v.u >> 16) & 1u);   // RNE
    return (unsigned short)(r >> 16);
}

// packed f32x2 -> bf16x2 (RNE), single HW instruction on gfx950
__device__ __forceinline__ unsigned cvtpk(float lo, float hi) {
    unsigned r;
    asm("v_cvt_pk_bf16_f32 %0, %1, %2" : "=v"(r) : "v"(lo), "v"(hi));
    return r;
}

// ---------------- prep: fold BNs, collapse W_ps@{W_ssig,W_tsig}, pack MFMA A-frags ----------------
__global__ __launch_bounds__(64) void stem_prep(
    const float* __restrict__ W_ssig, const float* __restrict__ b_ssig,
    const float* __restrict__ W_tsig, const float* __restrict__ b_tsig,
    const float* __restrict__ W_raw,  const float* __restrict__ b_raw,
    const float* __restrict__ W_ps,   const float* __restrict__ b_ps,
    const float* __restrict__ W_fu,   const float* __restrict__ b_fu,
    const float* __restrict__ g_raw, const float* __restrict__ be_raw,
    const float* __restrict__ m_raw, const float* __restrict__ v_raw,
    const float* __restrict__ g_ps,  const float* __restrict__ be_ps,
    const float* __restrict__ m_ps,  const float* __restrict__ v_ps,
    const float* __restrict__ g_fu,  const float* __restrict__ be_fu,
    const float* __restrict__ m_fu,  const float* __restrict__ v_fu,
    float* __restrict__ wsf, unsigned short* __restrict__ wsA1,
    unsigned short* __restrict__ wsA2, unsigned short* __restrict__ wsA3)
{
    const int l = threadIdx.x;         // 0..63
    const int f = blockIdx.x;
    if (f < 24) {
        // A1 frag f = h*12 + s*4 + to ; element b: W1[k=s*32+8*(l>>4)+b][o=to*16+(l&15)]
        const int h = f / 12, rem = f % 12, s = rem / 4, to = rem % 4;
        const int o = to*16 + (l & 15);
        const float sps = g_ps[o] / sqrtf(v_ps[o] + EPSF);
        const float* wp  = W_ps + o*128 + 64*h;
        const float* wsg = h ? W_tsig : W_ssig;
        for (int b = 0; b < 8; ++b) {
            const int k = s*32 + ((l >> 4) * 8) + b;
            float v = 0.f;
            if (k < 84) {
                float acc = 0.f;
                for (int c = 0; c < 64; ++c) acc = fmaf(wp[c], wsg[c*84 + k], acc);
                v = acc * sps;
            }
            wsA1[f*512 + l*8 + b] = f2bf(v);
        }
    } else if (f < 40) {
        // A2 frag q = s*4+to ; element b: Wf[c=s*32+8*(l>>4)+b][o] = sfu[o]*W_fu[o*128+c]
        const int q = f - 24, s = q / 4, to = q % 4;
        const int o = to*16 + (l & 15);
        const float sfu = g_fu[o] / sqrtf(v_fu[o] + EPSF);
        for (int b = 0; b < 8; ++b) {
            const int c = s*32 + ((l >> 4) * 8) + b;
            wsA2[q*512 + l*8 + b] = f2bf(W_fu[o*128 + c] * sfu);
        }
    } else if (f == 40) {
        const int o = l;
        const float sps = g_ps[o] / sqrtf(v_ps[o] + EPSF);
        float acc = b_ps[o] - m_ps[o];
        for (int c = 0; c < 64; ++c) {
            acc = fmaf(W_ps[o*128 + c],      b_ssig[c], acc);
            acc = fmaf(W_ps[o*128 + 64 + c], b_tsig[c], acc);
        }
        wsf[WS_B0 + o] = acc * sps + be_ps[o];
        const float sraw = g_raw[o] / sqrtf(v_raw[o] + EPSF);
        wsf[WS_BC + o] = (b_raw[o] - m_raw[o]) * sraw + be_raw[o];
        const float sfu = g_fu[o] / sqrtf(v_fu[o] + EPSF);
        wsf[WS_BF + o] = (b_fu[o] - m_fu[o]) * sfu + be_fu[o];
    } else {
        // A3 frag to = f-41 ; element b: k = 8*(l>>4)+b; Wc[k][o] = sraw[o]*W_raw[o*9+k] (k<9)
        const int to = f - 41;
        const int o = to*16 + (l & 15);
        const float sraw = g_raw[o] / sqrtf(v_raw[o] + EPSF);
        for (int b = 0; b < 8; ++b) {
            const int k = ((l >> 4) * 8) + b;
            wsA3[to*512 + l*8 + b] = (k < 9) ? f2bf(W_raw[o*9 + k] * sraw) : (unsigned short)0;
        }
    }
}

// FACTORED depth-3 signature step. sig = [S1(0..3)|S2(4..19)|S3(20..83)], static-indexed.
//   S3[ijk] += (S2old[ij] + fv_i*dh_j) * d_k ; S2[ij] = fma(S1_i+dh_i, d_j, S2[ij])
//   fv_i = S1_i + d_i/3 ; dh_i = 0.5*d_i ; S1 += d        (112 inst/step)
__device__ __forceinline__ void sig_step(float* __restrict__ sig, const float d[4])
{
    float* S1 = sig; float* S2 = sig + 4; float* S3 = sig + 20;
    float dh[4], fv[4];
#pragma unroll
    for (int i = 0; i < 4; ++i) dh[i] = 0.5f * d[i];
#pragma unroll
    for (int i = 0; i < 4; ++i) fv[i] = fmaf(d[i], (1.f/3.f), S1[i]);
    float h[16];
#pragma unroll
    for (int i = 0; i < 4; ++i)
#pragma unroll
        for (int j = 0; j < 4; ++j) h[i*4+j] = fmaf(fv[i], dh[j], S2[i*4+j]);  // OLD S2
#pragma unroll
    for (int i = 0; i < 4; ++i)
#pragma unroll
        for (int j = 0; j < 4; ++j) {
            const float hij = h[i*4+j];
#pragma unroll
            for (int k = 0; k < 4; ++k)
                S3[(i*4+j)*4+k] = fmaf(hij, d[k], S3[(i*4+j)*4+k]);
        }
    float q[4];
#pragma unroll
    for (int i = 0; i < 4; ++i) q[i] = S1[i] + dh[i];
#pragma unroll
    for (int i = 0; i < 4; ++i)
#pragma unroll
        for (int j = 0; j < 4; ++j) S2[i*4+j] = fmaf(q[i], d[j], S2[i*4+j]);
#pragma unroll
    for (int i = 0; i < 4; ++i) S1[i] += d[i];
}

// first step from zero state with d[3]==0: S1=d, S2=dh_i*d_j, S3=(d_i/3)*S2[jk]
__device__ __forceinline__ void sig_init(float* __restrict__ sig, float d0, float d1, float d2)
{
    const float dd[4] = { d0, d1, d2, 0.f };
#pragma unroll
    for (int i = 0; i < 4; ++i) sig[i] = dd[i];
#pragma unroll
    for (int i = 0; i < 4; ++i) {
        const float dh = 0.5f * dd[i];
#pragma unroll
        for (int j = 0; j < 4; ++j) sig[4 + i*4 + j] = dh * dd[j];
    }
#pragma unroll
    for (int i = 0; i < 4; ++i) {
        const float di3 = dd[i] * (1.f/3.f);
#pragma unroll
        for (int j = 0; j < 4; ++j)
#pragma unroll
            for (int k = 0; k < 4; ++k)
                sig[20 + (i*4+j)*4 + k] = di3 * sig[4 + j*4 + k];
    }
}

// grid: (4 t-chunks, 64 j, 32 b); block 64 = 1 wave; block owns t-cols [bx*64, bx*64+64).
// k-major LDS: slot s (16B per row) at byte s*1024 + row*16; 12 slots = 12288 B.
// conv computed via MFMA (K=9 padded to 32; xv in slots 8..11, bf16).
// ALL sigma input loads issued at kernel top (T14 issue-early): sigma_t's 21 loads'
// L2 latency hides under sigma_s's ~1200-cyc FMA chain via vmcnt-counted waits.
// Explicit __syncthreads() at every LDS W->R / R->W boundary (round-4 lesson).
__global__ __launch_bounds__(64, 3) void stem_main(
    const float* __restrict__ x, const int* __restrict__ path,
    const float* __restrict__ wsf, const unsigned short* __restrict__ wsA1,
    const unsigned short* __restrict__ wsA2, const unsigned short* __restrict__ wsA3,
    float* __restrict__ out)
{
    __shared__ char sb[12 * 1024];
    const int l  = threadIdx.x;                  // lane
    const int t  = blockIdx.x * 64 + l;          // global t for this thread's column
    const int j  = blockIdx.y;
    const int b  = blockIdx.z;
    const float* xb = x + (size_t)b * (3*64*256);

    const int lg = l >> 4;      // lane k-group
    const int li = l & 15;      // m/n index within tile
    char* const myw = sb + l*16;                 // write base: slot via immediate

    // ==== issue ALL sigma input loads up front (addresses depend only on j,t) ====
    float ps_[5][3];                              // spatial points
#pragma unroll
    for (int s = 0; s < 5; ++s) {
        const int jp = path[j*5 + s];             // wave-uniform
        ps_[s][0] = xb[(0*64 + jp)*256 + t];
        ps_[s][1] = xb[(1*64 + jp)*256 + t];
        ps_[s][2] = xb[(2*64 + jp)*256 + t];
    }
    float pt_[7][3];                              // temporal (scrambled window) points
#pragma unroll
    for (int k = 0; k < 7; ++k) {
        const int idx  = j*7 + k;
        const int jsrc = idx & 63;
        const int tl   = idx >> 6;
        const int ts   = min(max(t + tl - 3, 0), 255);
        pt_[k][0] = xb[(0*64 + jsrc)*256 + ts];
        pt_[k][1] = xb[(1*64 + jsrc)*256 + ts];
        pt_[k][2] = xb[(2*64 + jsrc)*256 + ts];
    }

    // ---- sigma_s: step-1 specialized, then 4 general steps (d3 = 0.25 literal) ----
    float sig[84];
    {
        sig_init(sig, ps_[0][0], ps_[0][1], ps_[0][2]);
#pragma unroll
        for (int s = 1; s < 5; ++s) {
            const float d[4] = { ps_[s][0]-ps_[s-1][0], ps_[s][1]-ps_[s-1][1],
                                 ps_[s][2]-ps_[s-1][2], 0.25f };
            sig_step(sig, d);
        }
    }
    // pack sigma_s k-major to LDS: slot v holds sig[8v..8v+7] (bf16), rows = lanes
    {
        unsigned uu[48];
#pragma unroll
        for (int i = 0; i < 42; ++i) uu[i] = cvtpk(sig[2*i], sig[2*i+1]);
#pragma unroll
        for (int i = 42; i < 48; ++i) uu[i] = 0u;
#pragma unroll
        for (int v = 0; v < 12; ++v) {
            uint32x4 w = { uu[4*v], uu[4*v+1], uu[4*v+2], uu[4*v+3] };
            *(uint32x4*)(myw + v*1024) = w;
        }
    }
    __syncthreads();                                      // W->R: sigma_s ready

    // ---- sigma_t NOW (before acc is born): data already in pt_ regs ----
    unsigned uuT[48];
    {
        sig_init(sig, pt_[0][0], pt_[0][1], pt_[0][2]);
#pragma unroll
        for (int k = 1; k < 7; ++k) {
            const float d[4] = { pt_[k][0]-pt_[k-1][0], pt_[k][1]-pt_[k-1][1],
                                 pt_[k][2]-pt_[k-1][2], (1.f/6.f) };
            sig_step(sig, d);
        }
#pragma unroll
        for (int i = 0; i < 42; ++i) uuT[i] = cvtpk(sig[2*i], sig[2*i+1]);
#pragma unroll
        for (int i = 42; i < 48; ++i) uuT[i] = 0u;
    }
    // sig (f32) is DEAD here -> acc can use the freed registers

    // ---- GEMM1a: acc = B0 + A(h=0) * sigma_s ----
    f32x4 acc[4][4];
#pragma unroll
    for (int to = 0; to < 4; ++to) {
        const f32x4 b0 = *(const f32x4*)(wsf + WS_B0 + to*16 + lg*4);
#pragma unroll
        for (int tt = 0; tt < 4; ++tt) acc[to][tt] = b0;
    }
    {
#pragma unroll
        for (int s = 0; s < 3; ++s) {
            bf16x8 A0 = *(const bf16x8*)(wsA1 + ((0*3+s)*4+0)*512 + l*8);
            bf16x8 A1 = *(const bf16x8*)(wsA1 + ((0*3+s)*4+1)*512 + l*8);
            bf16x8 A2 = *(const bf16x8*)(wsA1 + ((0*3+s)*4+2)*512 + l*8);
            bf16x8 A3 = *(const bf16x8*)(wsA1 + ((0*3+s)*4+3)*512 + l*8);
#pragma unroll
            for (int tt = 0; tt < 4; ++tt) {
                const bf16x8 B = *(const bf16x8*)(sb + (s*4+lg)*1024 + (tt*16+li)*16);
                acc[0][tt] = __builtin_amdgcn_mfma_f32_16x16x32_bf16(A0, B, acc[0][tt], 0, 0, 0);
                acc[1][tt] = __builtin_amdgcn_mfma_f32_16x16x32_bf16(A1, B, acc[1][tt], 0, 0, 0);
                acc[2][tt] = __builtin_amdgcn_mfma_f32_16x16x32_bf16(A2, B, acc[2][tt], 0, 0, 0);
                acc[3][tt] = __builtin_amdgcn_mfma_f32_16x16x32_bf16(A3, B, acc[3][tt], 0, 0, 0);
            }
        }
    }
    __syncthreads();                                      // R->W: done reading sigma_s

    // dump packed sigma_t regs -> LDS
    {
#pragma unroll
        for (int v = 0; v < 12; ++v) {
            uint32x4 w = { uuT[4*v], uuT[4*v+1], uuT[4*v+2], uuT[4*v+3] };
            *(uint32x4*)(myw + v*1024) = w;
        }
    }
    __syncthreads();                                      // W->R: sigma_t ready

    // conv window loads issued here (HBM latency hides under GEMM1b)
    float xv[9];
#pragma unroll
    for (int ci = 0; ci < 3; ++ci) {
        const float* xr = xb + (ci*64 + j)*256;
        xv[ci*3+0] = (t >= 1)   ? xr[t-1] : 0.f;
        xv[ci*3+1] = xr[t];
        xv[ci*3+2] = (t <= 254) ? xr[t+1] : 0.f;
    }

    // ---- GEMM1b: acc += A(h=1) * sigma_t ----
    {
#pragma unroll
        for (int s = 0; s < 3; ++s) {
            bf16x8 A0 = *(const bf16x8*)(wsA1 + ((1*3+s)*4+0)*512 + l*8);
            bf16x8 A1 = *(const bf16x8*)(wsA1 + ((1*3+s)*4+1)*512 + l*8);
            bf16x8 A2 = *(const bf16x8*)(wsA1 + ((1*3+s)*4+2)*512 + l*8);
            bf16x8 A3 = *(const bf16x8*)(wsA1 + ((1*3+s)*4+3)*512 + l*8);
#pragma unroll
            for (int tt = 0; tt < 4; ++tt) {
                const bf16x8 B = *(const bf16x8*)(sb + (s*4+lg)*1024 + (tt*16+li)*16);
                acc[0][tt] = __builtin_amdgcn_mfma_f32_16x16x32_bf16(A0, B, acc[0][tt], 0, 0, 0);
                acc[1][tt] = __builtin_amdgcn_mfma_f32_16x16x32_bf16(A1, B, acc[1][tt], 0, 0, 0);
                acc[2][tt] = __builtin_amdgcn_mfma_f32_16x16x32_bf16(A2, B, acc[2][tt], 0, 0, 0);
                acc[3][tt] = __builtin_amdgcn_mfma_f32_16x16x32_bf16(A3, B, acc[3][tt], 0, 0, 0);
            }
        }
    }
    __syncthreads();                                      // R->W: done reading sigma_t

    // ---- ps pack: u_ps[row][o] = bf16(relu(acc)), k-major slots 0..7 (slot = o>>3) ----
#pragma unroll
    for (int to = 0; to < 4; ++to) {
#pragma unroll
        for (int tt = 0; tt < 4; ++tt) {
            const unsigned w0 = cvtpk(fmaxf(acc[to][tt][0], 0.f), fmaxf(acc[to][tt][1], 0.f));
            const unsigned w1 = cvtpk(fmaxf(acc[to][tt][2], 0.f), fmaxf(acc[to][tt][3], 0.f));
            uint32x2 w = { w0, w1 };
            *(uint32x2*)(sb + (to*2+(lg>>1))*1024 + (tt*16+li)*16 + ((lg&1)<<3)) = w;
        }
    }
    // ---- xv pack (bf16) -> slots 8..11 (K=32, zeros beyond k=8) ----
    {
        unsigned xu[16];
        xu[0] = cvtpk(xv[0], xv[1]); xu[1] = cvtpk(xv[2], xv[3]);
        xu[2] = cvtpk(xv[4], xv[5]); xu[3] = cvtpk(xv[6], xv[7]);
        xu[4] = cvtpk(xv[8], 0.f);
#pragma unroll
        for (int i = 5; i < 16; ++i) xu[i] = 0u;
#pragma unroll
        for (int v = 0; v < 4; ++v) {
            uint32x4 w = { xu[4*v], xu[4*v+1], xu[4*v+2], xu[4*v+3] };
            *(uint32x4*)(myw + (8+v)*1024) = w;
        }
    }
    __syncthreads();                                      // W->R: u_ps + xv ready

    // ---- GEMM-conv via MFMA: acc = BC + Wc * xv  (K=32, slots 8..11, A3 frags) ----
#pragma unroll
    for (int to = 0; to < 4; ++to) {
        const f32x4 bc4 = *(const f32x4*)(wsf + WS_BC + to*16 + lg*4);
#pragma unroll
        for (int tt = 0; tt < 4; ++tt) acc[to][tt] = bc4;
    }
    {
        bf16x8 A0 = *(const bf16x8*)(wsA3 + 0*512 + l*8);
        bf16x8 A1 = *(const bf16x8*)(wsA3 + 1*512 + l*8);
        bf16x8 A2 = *(const bf16x8*)(wsA3 + 2*512 + l*8);
        bf16x8 A3 = *(const bf16x8*)(wsA3 + 3*512 + l*8);
#pragma unroll
        for (int tt = 0; tt < 4; ++tt) {
            const bf16x8 B = *(const bf16x8*)(sb + (8+lg)*1024 + (tt*16+li)*16);
            acc[0][tt] = __builtin_amdgcn_mfma_f32_16x16x32_bf16(A0, B, acc[0][tt], 0, 0, 0);
            acc[1][tt] = __builtin_amdgcn_mfma_f32_16x16x32_bf16(A1, B, acc[1][tt], 0, 0, 0);
            acc[2][tt] = __builtin_amdgcn_mfma_f32_16x16x32_bf16(A2, B, acc[2][tt], 0, 0, 0);
            acc[3][tt] = __builtin_amdgcn_mfma_f32_16x16x32_bf16(A3, B, acc[3][tt], 0, 0, 0);
        }
    }
    // relu-pack conv result to regs (same [row][o] mapping as ps pack, held in cu)
    unsigned cu[32];
#pragma unroll
    for (int to = 0; to < 4; ++to)
#pragma unroll
        for (int tt = 0; tt < 4; ++tt) {
            cu[(to*4+tt)*2+0] = cvtpk(fmaxf(acc[to][tt][0], 0.f), fmaxf(acc[to][tt][1], 0.f));
            cu[(to*4+tt)*2+1] = cvtpk(fmaxf(acc[to][tt][2], 0.f), fmaxf(acc[to][tt][3], 0.f));
        }

    // ---- GEMM2-ps: acc = BF + Wf_hi^T u_ps  (A2 frags q = 8..15, slots 0..7) ----
#pragma unroll
    for (int to = 0; to < 4; ++to) {
        const f32x4 bf4 = *(const f32x4*)(wsf + WS_BF + to*16 + lg*4);
#pragma unroll
        for (int tt = 0; tt < 4; ++tt) acc[to][tt] = bf4;
    }
    {
#pragma unroll
        for (int s = 0; s < 2; ++s) {
            bf16x8 A0 = *(const bf16x8*)(wsA2 + ((s+2)*4+0)*512 + l*8);
            bf16x8 A1 = *(const bf16x8*)(wsA2 + ((s+2)*4+1)*512 + l*8);
            bf16x8 A2 = *(const bf16x8*)(wsA2 + ((s+2)*4+2)*512 + l*8);
            bf16x8 A3 = *(const bf16x8*)(wsA2 + ((s+2)*4+3)*512 + l*8);
#pragma unroll
            for (int tt = 0; tt < 4; ++tt) {
                const bf16x8 B = *(const bf16x8*)(sb + (s*4+lg)*1024 + (tt*16+li)*16);
                acc[0][tt] = __builtin_amdgcn_mfma_f32_16x16x32_bf16(A0, B, acc[0][tt], 0, 0, 0);
                acc[1][tt] = __builtin_amdgcn_mfma_f32_16x16x32_bf16(A1, B, acc[1][tt], 0, 0, 0);
                acc[2][tt] = __builtin_amdgcn_mfma_f32_16x16x32_bf16(A2, B, acc[2][tt], 0, 0, 0);
                acc[3][tt] = __builtin_amdgcn_mfma_f32_16x16x32_bf16(A3, B, acc[3][tt], 0, 0, 0);
            }
        }
    }
    __syncthreads();                                      // R->W: done reading u_ps

    // ---- conv store: u_conv[row][o] from cu -> slots 0..7 (same map as ps pack) ----
#pragma unroll
    for (int to = 0; to < 4; ++to)
#pragma unroll
        for (int tt = 0; tt < 4; ++tt) {
            uint32x2 w = { cu[(to*4+tt)*2+0], cu[(to*4+tt)*2+1] };
            *(uint32x2*)(sb + (to*2+(lg>>1))*1024 + (tt*16+li)*16 + ((lg&1)<<3)) = w;
        }
    __syncthreads();                                      // W->R: u_conv ready

    // ---- GEMM2-conv: acc += Wf_lo^T u_conv  (A2 frags q = 0..7, slots 0..7) ----
    {
#pragma unroll
        for (int s = 0; s < 2; ++s) {
            bf16x8 A0 = *(const bf16x8*)(wsA2 + (s*4+0)*512 + l*8);
            bf16x8 A1 = *(const bf16x8*)(wsA2 + (s*4+1)*512 + l*8);
            bf16x8 A2 = *(const bf16x8*)(wsA2 + (s*4+2)*512 + l*8);
            bf16x8 A3 = *(const bf16x8*)(wsA2 + (s*4+3)*512 + l*8);
#pragma unroll
            for (int tt = 0; tt < 4; ++tt) {
                const bf16x8 B = *(const bf16x8*)(sb + (s*4+lg)*1024 + (tt*16+li)*16);
                acc[0][tt] = __builtin_amdgcn_mfma_f32_16x16x32_bf16(A0, B, acc[0][tt], 0, 0, 0);
                acc[1][tt] = __builtin_amdgcn_mfma_f32_16x16x32_bf16(A1, B, acc[1][tt], 0, 0, 0);
                acc[2][tt] = __builtin_amdgcn_mfma_f32_16x16x32_bf16(A2, B, acc[2][tt], 0, 0, 0);
                acc[3][tt] = __builtin_amdgcn_mfma_f32_16x16x32_bf16(A3, B, acc[3][tt], 0, 0, 0);
            }
        }
    }

    // ---- final epilogue: relu (bias already in C-init), store out[b][o][j][t] ----
#pragma unroll
    for (int to = 0; to < 4; ++to) {
#pragma unroll
        for (int tt = 0; tt < 4; ++tt) {
            const int tg = blockIdx.x*64 + tt*16 + li;
#pragma unroll
            for (int r = 0; r < 4; ++r) {
                const int o = to*16 + lg*4 + r;
                out[(((size_t)b*64 + o)*64 + j)*256 + tg] = fmaxf(acc[to][tt][r], 0.f);
            }
        }
    }
}

extern "C" void kernel_launch(void* const* d_in, const int* in_sizes, int n_in,
                              void* d_out, int out_size, void* d_ws, size_t ws_size,
                              hipStream_t stream)
{
    const float* x      = (const float*)d_in[0];
    const int*   path   = (const int*)  d_in[1];
    const float* W_ssig = (const float*)d_in[2];
    const float* b_ssig = (const float*)d_in[3];
    const float* W_tsig = (const float*)d_in[4];
    const float* b_tsig = (const float*)d_in[5];
    const float* W_raw  = (const float*)d_in[6];
    const float* b_raw  = (const float*)d_in[7];
    const float* W_ps   = (const float*)d_in[8];
    const float* b_ps   = (const float*)d_in[9];
    const float* W_fu   = (const float*)d_in[10];
    const float* b_fu   = (const float*)d_in[11];
    const float* g_raw  = (const float*)d_in[12];
    const float* be_raw = (const float*)d_in[13];
    const float* m_raw  = (const float*)d_in[14];
    const float* v_raw  = (const float*)d_in[15];
    const float* g_ps   = (const float*)d_in[16];
    const float* be_ps  = (const float*)d_in[17];
    const float* m_ps   = (const float*)d_in[18];
    const float* v_ps   = (const float*)d_in[19];
    const float* g_fu   = (const float*)d_in[20];
    const float* be_fu  = (const float*)d_in[21];
    const float* m_fu   = (const float*)d_in[22];
    const float* v_fu   = (const float*)d_in[23];
    float* out = (float*)d_out;

    float*          wsf  = (float*)d_ws;
    unsigned short* wsA1 = (unsigned short*)((char*)d_ws + 4096);
    unsigned short* wsA2 = (unsigned short*)((char*)d_ws + 28672);
    unsigned short* wsA3 = (unsigned short*)((char*)d_ws + 45056);

    stem_prep<<<45, 64, 0, stream>>>(W_ssig, b_ssig, W_tsig, b_tsig, W_raw, b_raw,
                                     W_ps, b_ps, W_fu, b_fu,
                                     g_raw, be_raw, m_raw, v_raw,
                                     g_ps, be_ps, m_ps, v_ps,
                                     g_fu, be_fu, m_fu, v_fu, wsf, wsA1, wsA2, wsA3);

    dim3 grid(4, 64, 32);   // (t-chunks, J, B)
    stem_main<<<grid, 64, 0, stream>>>(x, path, wsf, wsA1, wsA2, wsA3, out);
}

// Round 13
// 60.565 us; speedup vs baseline: 1.3979x; 1.0581x over previous
//
#include <hip/hip_runtime.h>
#include <hip/hip_fp16.h>
#include <cstdint>

#define EPSF 1e-5f

typedef __attribute__((ext_vector_type(8))) _Float16  f16x8;
typedef __attribute__((ext_vector_type(4))) float     f32x4;
typedef __attribute__((ext_vector_type(4))) unsigned int uint32x4;
typedef __attribute__((ext_vector_type(2))) unsigned int uint32x2;

// ---- workspace layout ----
// floats (at byte 0): B0[64] @0, BC[64] @64, BF[64] @128
#define WS_B0 0
#define WS_BC 64
#define WS_BF 128
// f16 A-fragments: wsA1 at byte 4096  (24 frags * 512 = 12288 ushort)
//                  wsA2 at byte 28672 (16 frags * 512 =  8192 ushort)
//                  wsA3 at byte 45056 ( 4 frags * 512 =  2048 ushort)  conv K=32(pad from 9)

__device__ __forceinline__ unsigned short f2h(float f) {
    __half h = __float2half(f);              // RNE
    return *reinterpret_cast<unsigned short*>(&h);
}

// f32 pair -> f16 pair (RTZ), single instruction
__device__ __forceinline__ unsigned cvtpk_h(float lo, float hi) {
    unsigned r;
    asm("v_cvt_pkrtz_f16_f32 %0, %1, %2" : "=v"(r) : "v"(lo), "v"(hi));
    return r;
}

// ---- packed f16 VOP3P helpers (TRUE dual-rate on CDNA, unlike pk_f32 — round-9 lesson).
// op_sel folds scalar broadcast of src0 into the op for free.
__device__ __forceinline__ unsigned pkfma(unsigned a, unsigned b, unsigned c) {
    unsigned d; asm("v_pk_fma_f16 %0, %1, %2, %3" : "=v"(d) : "v"(a), "v"(b), "v"(c)); return d;
}
__device__ __forceinline__ unsigned pkfma_lo(unsigned a, unsigned b, unsigned c) {  // bcast a.lo
    unsigned d; asm("v_pk_fma_f16 %0, %1, %2, %3 op_sel_hi:[0,1,1]" : "=v"(d) : "v"(a), "v"(b), "v"(c)); return d;
}
__device__ __forceinline__ unsigned pkfma_hi(unsigned a, unsigned b, unsigned c) {  // bcast a.hi
    unsigned d; asm("v_pk_fma_f16 %0, %1, %2, %3 op_sel:[1,0,0]" : "=v"(d) : "v"(a), "v"(b), "v"(c)); return d;
}
__device__ __forceinline__ unsigned pkmul(unsigned a, unsigned b) {
    unsigned d; asm("v_pk_mul_f16 %0, %1, %2" : "=v"(d) : "v"(a), "v"(b)); return d;
}
__device__ __forceinline__ unsigned pkmul_lo(unsigned a, unsigned b) {              // bcast a.lo
    unsigned d; asm("v_pk_mul_f16 %0, %1, %2 op_sel_hi:[0,1]" : "=v"(d) : "v"(a), "v"(b)); return d;
}
__device__ __forceinline__ unsigned pkmul_hi(unsigned a, unsigned b) {              // bcast a.hi
    unsigned d; asm("v_pk_mul_f16 %0, %1, %2 op_sel:[1,0]" : "=v"(d) : "v"(a), "v"(b)); return d;
}
__device__ __forceinline__ unsigned pkadd(unsigned a, unsigned b) {
    unsigned d; asm("v_pk_add_f16 %0, %1, %2" : "=v"(d) : "v"(a), "v"(b)); return d;
}

#define C_HALF2  0x38003800u   // (0.5h, 0.5h)
#define C_THIRD2 0x35553555u   // (1/3 h, 1/3 h)

// ---------------- prep: fold BNs, collapse W_ps@{W_ssig,W_tsig}, pack MFMA A-frags (f16) ----------------
__global__ __launch_bounds__(64) void stem_prep(
    const float* __restrict__ W_ssig, const float* __restrict__ b_ssig,
    const float* __restrict__ W_tsig, const float* __restrict__ b_tsig,
    const float* __restrict__ W_raw,  const float* __restrict__ b_raw,
    const float* __restrict__ W_ps,   const float* __restrict__ b_ps,
    const float* __restrict__ W_fu,   const float* __restrict__ b_fu,
    const float* __restrict__ g_raw, const float* __restrict__ be_raw,
    const float* __restrict__ m_raw, const float* __restrict__ v_raw,
    const float* __restrict__ g_ps,  const float* __restrict__ be_ps,
    const float* __restrict__ m_ps,  const float* __restrict__ v_ps,
    const float* __restrict__ g_fu,  const float* __restrict__ be_fu,
    const float* __restrict__ m_fu,  const float* __restrict__ v_fu,
    float* __restrict__ wsf, unsigned short* __restrict__ wsA1,
    unsigned short* __restrict__ wsA2, unsigned short* __restrict__ wsA3)
{
    const int l = threadIdx.x;         // 0..63
    const int f = blockIdx.x;
    if (f < 24) {
        // A1 frag f = h*12 + s*4 + to ; element b: W1[k=s*32+8*(l>>4)+b][o=to*16+(l&15)]
        const int h = f / 12, rem = f % 12, s = rem / 4, to = rem % 4;
        const int o = to*16 + (l & 15);
        const float sps = g_ps[o] / sqrtf(v_ps[o] + EPSF);
        const float* wp  = W_ps + o*128 + 64*h;
        const float* wsg = h ? W_tsig : W_ssig;
        for (int b = 0; b < 8; ++b) {
            const int k = s*32 + ((l >> 4) * 8) + b;
            float v = 0.f;
            if (k < 84) {
                float acc = 0.f;
                for (int c = 0; c < 64; ++c) acc = fmaf(wp[c], wsg[c*84 + k], acc);
                v = acc * sps;
            }
            wsA1[f*512 + l*8 + b] = f2h(v);
        }
    } else if (f < 40) {
        // A2 frag q = s*4+to ; element b: Wf[c=s*32+8*(l>>4)+b][o] = sfu[o]*W_fu[o*128+c]
        const int q = f - 24, s = q / 4, to = q % 4;
        const int o = to*16 + (l & 15);
        const float sfu = g_fu[o] / sqrtf(v_fu[o] + EPSF);
        for (int b = 0; b < 8; ++b) {
            const int c = s*32 + ((l >> 4) * 8) + b;
            wsA2[q*512 + l*8 + b] = f2h(W_fu[o*128 + c] * sfu);
        }
    } else if (f == 40) {
        const int o = l;
        const float sps = g_ps[o] / sqrtf(v_ps[o] + EPSF);
        float acc = b_ps[o] - m_ps[o];
        for (int c = 0; c < 64; ++c) {
            acc = fmaf(W_ps[o*128 + c],      b_ssig[c], acc);
            acc = fmaf(W_ps[o*128 + 64 + c], b_tsig[c], acc);
        }
        wsf[WS_B0 + o] = acc * sps + be_ps[o];
        const float sraw = g_raw[o] / sqrtf(v_raw[o] + EPSF);
        wsf[WS_BC + o] = (b_raw[o] - m_raw[o]) * sraw + be_raw[o];
        const float sfu = g_fu[o] / sqrtf(v_fu[o] + EPSF);
        wsf[WS_BF + o] = (b_fu[o] - m_fu[o]) * sfu + be_fu[o];
    } else {
        // A3 frag to = f-41 ; element b: k = 8*(l>>4)+b; Wc[k][o] = sraw[o]*W_raw[o*9+k] (k<9)
        const int to = f - 41;
        const int o = to*16 + (l & 15);
        const float sraw = g_raw[o] / sqrtf(v_raw[o] + EPSF);
        for (int b = 0; b < 8; ++b) {
            const int k = ((l >> 4) * 8) + b;
            wsA3[to*512 + l*8 + b] = (k < 9) ? f2h(W_raw[o*9 + k] * sraw) : (unsigned short)0;
        }
    }
}

// ---- packed-f16 factored sig step. State S[42] u32 = f16 pairs along last index:
// S[0..1]=S1, S[2..9]=S2 (S2[i*2+p]), S[10..41]=S3 (S3[(i*4+j)*2+p]).
//   h_ij = fma(fv_i, dh_j, S2old_ij); S3 += h_ij (x) d; S2 += (S1+dh)_i (x) d; S1 += d
// 56 pk insts/step (was 108 f32). op_sel broadcasts are free.
__device__ __forceinline__ void sig_step_h(unsigned* __restrict__ S, unsigned d01, unsigned d23)
{
    const unsigned dh0 = pkmul(C_HALF2, d01), dh1 = pkmul(C_HALF2, d23);
    const unsigned fv0 = pkfma(d01, C_THIRD2, S[0]);
    const unsigned fv1 = pkfma(d23, C_THIRD2, S[1]);
    unsigned h[8];                                // h[i*2+p], OLD S2
    h[0] = pkfma_lo(fv0, dh0, S[2]); h[1] = pkfma_lo(fv0, dh1, S[3]);
    h[2] = pkfma_hi(fv0, dh0, S[4]); h[3] = pkfma_hi(fv0, dh1, S[5]);
    h[4] = pkfma_lo(fv1, dh0, S[6]); h[5] = pkfma_lo(fv1, dh1, S[7]);
    h[6] = pkfma_hi(fv1, dh0, S[8]); h[7] = pkfma_hi(fv1, dh1, S[9]);
#pragma unroll
    for (int i = 0; i < 4; ++i) {
#pragma unroll
        for (int j = 0; j < 4; ++j) {
            const int hr = i*2 + (j>>1);
            const int base = 10 + (i*4+j)*2;
            if (j & 1) { S[base]   = pkfma_hi(h[hr], d01, S[base]);
                         S[base+1] = pkfma_hi(h[hr], d23, S[base+1]); }
            else       { S[base]   = pkfma_lo(h[hr], d01, S[base]);
                         S[base+1] = pkfma_lo(h[hr], d23, S[base+1]); }
        }
    }
    const unsigned q0 = pkadd(S[0], dh0), q1 = pkadd(S[1], dh1);   // OLD S1
    S[2] = pkfma_lo(q0, d01, S[2]); S[3] = pkfma_lo(q0, d23, S[3]);
    S[4] = pkfma_hi(q0, d01, S[4]); S[5] = pkfma_hi(q0, d23, S[5]);
    S[6] = pkfma_lo(q1, d01, S[6]); S[7] = pkfma_lo(q1, d23, S[7]);
    S[8] = pkfma_hi(q1, d01, S[8]); S[9] = pkfma_hi(q1, d23, S[9]);
    S[0] = pkadd(S[0], d01); S[1] = pkadd(S[1], d23);
}

// first step from zero state (d3==0 encoded in d23.hi): S1=d, S2=dh_i*d_j, S3=(d_i/3)*S2[jk]
__device__ __forceinline__ void sig_init_h(unsigned* __restrict__ S, unsigned d01, unsigned d23)
{
    S[0] = d01; S[1] = d23;
    const unsigned dh0 = pkmul(C_HALF2, d01), dh1 = pkmul(C_HALF2, d23);
    S[2] = pkmul_lo(dh0, d01); S[3] = pkmul_lo(dh0, d23);
    S[4] = pkmul_hi(dh0, d01); S[5] = pkmul_hi(dh0, d23);
    S[6] = pkmul_lo(dh1, d01); S[7] = pkmul_lo(dh1, d23);
    S[8] = pkmul_hi(dh1, d01); S[9] = pkmul_hi(dh1, d23);
    const unsigned td0 = pkmul(C_THIRD2, d01), td1 = pkmul(C_THIRD2, d23);
#pragma unroll
    for (int i = 0; i < 4; ++i) {
        const unsigned tdr = (i < 2) ? td0 : td1;
#pragma unroll
        for (int j = 0; j < 4; ++j) {
            const int base = 10 + (i*4+j)*2;
            if (i & 1) { S[base]   = pkmul_hi(tdr, S[2+j*2]);
                         S[base+1] = pkmul_hi(tdr, S[2+j*2+1]); }
            else       { S[base]   = pkmul_lo(tdr, S[2+j*2]);
                         S[base+1] = pkmul_lo(tdr, S[2+j*2+1]); }
        }
    }
}

// grid: (4 t-chunks, 64 j, 32 b); block 64 = 1 wave; block owns t-cols [bx*64, bx*64+64).
// k-major LDS: slot s (16B per row) at byte s*1024 + row*16; 12 slots = 12288 B.
// sigma state is f16 pairs -> stored DIRECTLY to LDS (no conversion pass).
// conv via MFMA (K=9 pad 32, xv slots 8..11). All MFMAs f16-input (same rate as bf16,
// tighter eps). Explicit __syncthreads() at every LDS W->R / R->W boundary.
__global__ __launch_bounds__(64, 3) void stem_main(
    const float* __restrict__ x, const int* __restrict__ path,
    const float* __restrict__ wsf, const unsigned short* __restrict__ wsA1,
    const unsigned short* __restrict__ wsA2, const unsigned short* __restrict__ wsA3,
    float* __restrict__ out)
{
    __shared__ char sb[12 * 1024];
    const int l  = threadIdx.x;                  // lane
    const int t  = blockIdx.x * 64 + l;          // global t for this thread's column
    const int j  = blockIdx.y;
    const int b  = blockIdx.z;
    const float* xb = x + (size_t)b * (3*64*256);

    const int lg = l >> 4;      // lane k-group
    const int li = l & 15;      // m/n index within tile
    char* const myw = sb + l*16;                 // write base: slot via immediate

    // ==== issue ALL sigma input loads up front (addresses depend only on j,t) ====
    float ps_[5][3];
#pragma unroll
    for (int s = 0; s < 5; ++s) {
        const int jp = path[j*5 + s];             // wave-uniform
        ps_[s][0] = xb[(0*64 + jp)*256 + t];
        ps_[s][1] = xb[(1*64 + jp)*256 + t];
        ps_[s][2] = xb[(2*64 + jp)*256 + t];
    }
    float pt_[7][3];
#pragma unroll
    for (int k = 0; k < 7; ++k) {
        const int idx  = j*7 + k;
        const int jsrc = idx & 63;
        const int tl   = idx >> 6;
        const int ts   = min(max(t + tl - 3, 0), 255);
        pt_[k][0] = xb[(0*64 + jsrc)*256 + ts];
        pt_[k][1] = xb[(1*64 + jsrc)*256 + ts];
        pt_[k][2] = xb[(2*64 + jsrc)*256 + ts];
    }

    unsigned S[42];

    // ---- sigma_s: init (d3=0), then 4 steps with d3 = 0.25 ----
    sig_init_h(S, cvtpk_h(ps_[0][0], ps_[0][1]), cvtpk_h(ps_[0][2], 0.f));
#pragma unroll
    for (int s = 1; s < 5; ++s) {
        const unsigned d01 = cvtpk_h(ps_[s][0]-ps_[s-1][0], ps_[s][1]-ps_[s-1][1]);
        const unsigned d23 = cvtpk_h(ps_[s][2]-ps_[s-1][2], 0.25f);
        sig_step_h(S, d01, d23);
    }
    // store sigma_s DIRECTLY (f16 pairs, linear k order): slots 0..9 full, 10 half, 11 zero
    {
#pragma unroll
        for (int v = 0; v < 10; ++v) {
            uint32x4 w = { S[4*v], S[4*v+1], S[4*v+2], S[4*v+3] };
            *(uint32x4*)(myw + v*1024) = w;
        }
        uint32x4 w10 = { S[40], S[41], 0u, 0u }; *(uint32x4*)(myw + 10*1024) = w10;
        uint32x4 w11 = { 0u, 0u, 0u, 0u };       *(uint32x4*)(myw + 11*1024) = w11;
    }
    __syncthreads();                                      // W->R: sigma_s ready

    // ---- sigma_t NOW (before acc is born); state stays in S regs across GEMM1a ----
    sig_init_h(S, cvtpk_h(pt_[0][0], pt_[0][1]), cvtpk_h(pt_[0][2], 0.f));
#pragma unroll
    for (int k = 1; k < 7; ++k) {
        const unsigned d01 = cvtpk_h(pt_[k][0]-pt_[k-1][0], pt_[k][1]-pt_[k-1][1]);
        const unsigned d23 = cvtpk_h(pt_[k][2]-pt_[k-1][2], (1.f/6.f));
        sig_step_h(S, d01, d23);
    }

    // ---- GEMM1a: acc = B0 + A(h=0) * sigma_s ----
    f32x4 acc[4][4];
#pragma unroll
    for (int to = 0; to < 4; ++to) {
        const f32x4 b0 = *(const f32x4*)(wsf + WS_B0 + to*16 + lg*4);
#pragma unroll
        for (int tt = 0; tt < 4; ++tt) acc[to][tt] = b0;
    }
    {
#pragma unroll
        for (int s = 0; s < 3; ++s) {
            f16x8 A0 = *(const f16x8*)(wsA1 + ((0*3+s)*4+0)*512 + l*8);
            f16x8 A1 = *(const f16x8*)(wsA1 + ((0*3+s)*4+1)*512 + l*8);
            f16x8 A2 = *(const f16x8*)(wsA1 + ((0*3+s)*4+2)*512 + l*8);
            f16x8 A3 = *(const f16x8*)(wsA1 + ((0*3+s)*4+3)*512 + l*8);
#pragma unroll
            for (int tt = 0; tt < 4; ++tt) {
                const f16x8 B = *(const f16x8*)(sb + (s*4+lg)*1024 + (tt*16+li)*16);
                acc[0][tt] = __builtin_amdgcn_mfma_f32_16x16x32_f16(A0, B, acc[0][tt], 0, 0, 0);
                acc[1][tt] = __builtin_amdgcn_mfma_f32_16x16x32_f16(A1, B, acc[1][tt], 0, 0, 0);
                acc[2][tt] = __builtin_amdgcn_mfma_f32_16x16x32_f16(A2, B, acc[2][tt], 0, 0, 0);
                acc[3][tt] = __builtin_amdgcn_mfma_f32_16x16x32_f16(A3, B, acc[3][tt], 0, 0, 0);
            }
        }
    }
    __syncthreads();                                      // R->W: done reading sigma_s

    // dump sigma_t state -> LDS slots 0..10 (slot 11 zeros persist)
    {
#pragma unroll
        for (int v = 0; v < 10; ++v) {
            uint32x4 w = { S[4*v], S[4*v+1], S[4*v+2], S[4*v+3] };
            *(uint32x4*)(myw + v*1024) = w;
        }
        uint32x4 w10 = { S[40], S[41], 0u, 0u }; *(uint32x4*)(myw + 10*1024) = w10;
    }
    __syncthreads();                                      // W->R: sigma_t ready

    // conv window loads issued here (HBM latency hides under GEMM1b)
    float xv[9];
#pragma unroll
    for (int ci = 0; ci < 3; ++ci) {
        const float* xr = xb + (ci*64 + j)*256;
        xv[ci*3+0] = (t >= 1)   ? xr[t-1] : 0.f;
        xv[ci*3+1] = xr[t];
        xv[ci*3+2] = (t <= 254) ? xr[t+1] : 0.f;
    }

    // ---- GEMM1b: acc += A(h=1) * sigma_t ----
    {
#pragma unroll
        for (int s = 0; s < 3; ++s) {
            f16x8 A0 = *(const f16x8*)(wsA1 + ((1*3+s)*4+0)*512 + l*8);
            f16x8 A1 = *(const f16x8*)(wsA1 + ((1*3+s)*4+1)*512 + l*8);
            f16x8 A2 = *(const f16x8*)(wsA1 + ((1*3+s)*4+2)*512 + l*8);
            f16x8 A3 = *(const f16x8*)(wsA1 + ((1*3+s)*4+3)*512 + l*8);
#pragma unroll
            for (int tt = 0; tt < 4; ++tt) {
                const f16x8 B = *(const f16x8*)(sb + (s*4+lg)*1024 + (tt*16+li)*16);
                acc[0][tt] = __builtin_amdgcn_mfma_f32_16x16x32_f16(A0, B, acc[0][tt], 0, 0, 0);
                acc[1][tt] = __builtin_amdgcn_mfma_f32_16x16x32_f16(A1, B, acc[1][tt], 0, 0, 0);
                acc[2][tt] = __builtin_amdgcn_mfma_f32_16x16x32_f16(A2, B, acc[2][tt], 0, 0, 0);
                acc[3][tt] = __builtin_amdgcn_mfma_f32_16x16x32_f16(A3, B, acc[3][tt], 0, 0, 0);
            }
        }
    }
    __syncthreads();                                      // R->W: done reading sigma_t

    // ---- ps pack: u_ps[row][o] = f16(relu(acc)), k-major slots 0..7 (slot = o>>3) ----
#pragma unroll
    for (int to = 0; to < 4; ++to) {
#pragma unroll
        for (int tt = 0; tt < 4; ++tt) {
            const unsigned w0 = cvtpk_h(fmaxf(acc[to][tt][0], 0.f), fmaxf(acc[to][tt][1], 0.f));
            const unsigned w1 = cvtpk_h(fmaxf(acc[to][tt][2], 0.f), fmaxf(acc[to][tt][3], 0.f));
            uint32x2 w = { w0, w1 };
            *(uint32x2*)(sb + (to*2+(lg>>1))*1024 + (tt*16+li)*16 + ((lg&1)<<3)) = w;
        }
    }
    // ---- xv pack (f16) -> slots 8..11 (K=32, zeros beyond k=8) ----
    {
        unsigned xu[16];
        xu[0] = cvtpk_h(xv[0], xv[1]); xu[1] = cvtpk_h(xv[2], xv[3]);
        xu[2] = cvtpk_h(xv[4], xv[5]); xu[3] = cvtpk_h(xv[6], xv[7]);
        xu[4] = cvtpk_h(xv[8], 0.f);
#pragma unroll
        for (int i = 5; i < 16; ++i) xu[i] = 0u;
#pragma unroll
        for (int v = 0; v < 4; ++v) {
            uint32x4 w = { xu[4*v], xu[4*v+1], xu[4*v+2], xu[4*v+3] };
            *(uint32x4*)(myw + (8+v)*1024) = w;
        }
    }
    __syncthreads();                                      // W->R: u_ps + xv ready

    // ---- GEMM-conv via MFMA: acc = BC + Wc * xv  (K=32, slots 8..11, A3 frags) ----
#pragma unroll
    for (int to = 0; to < 4; ++to) {
        const f32x4 bc4 = *(const f32x4*)(wsf + WS_BC + to*16 + lg*4);
#pragma unroll
        for (int tt = 0; tt < 4; ++tt) acc[to][tt] = bc4;
    }
    {
        f16x8 A0 = *(const f16x8*)(wsA3 + 0*512 + l*8);
        f16x8 A1 = *(const f16x8*)(wsA3 + 1*512 + l*8);
        f16x8 A2 = *(const f16x8*)(wsA3 + 2*512 + l*8);
        f16x8 A3 = *(const f16x8*)(wsA3 + 3*512 + l*8);
#pragma unroll
        for (int tt = 0; tt < 4; ++tt) {
            const f16x8 B = *(const f16x8*)(sb + (8+lg)*1024 + (tt*16+li)*16);
            acc[0][tt] = __builtin_amdgcn_mfma_f32_16x16x32_f16(A0, B, acc[0][tt], 0, 0, 0);
            acc[1][tt] = __builtin_amdgcn_mfma_f32_16x16x32_f16(A1, B, acc[1][tt], 0, 0, 0);
            acc[2][tt] = __builtin_amdgcn_mfma_f32_16x16x32_f16(A2, B, acc[2][tt], 0, 0, 0);
            acc[3][tt] = __builtin_amdgcn_mfma_f32_16x16x32_f16(A3, B, acc[3][tt], 0, 0, 0);
        }
    }
    // relu-pack conv result to regs (same [row][o] mapping as ps pack, held in cu)
    unsigned cu[32];
#pragma unroll
    for (int to = 0; to < 4; ++to)
#pragma unroll
        for (int tt = 0; tt < 4; ++tt) {
            cu[(to*4+tt)*2+0] = cvtpk_h(fmaxf(acc[to][tt][0], 0.f), fmaxf(acc[to][tt][1], 0.f));
            cu[(to*4+tt)*2+1] = cvtpk_h(fmaxf(acc[to][tt][2], 0.f), fmaxf(acc[to][tt][3], 0.f));
        }

    // ---- GEMM2-ps: acc = BF + Wf_hi^T u_ps  (A2 frags q = 8..15, slots 0..7) ----
#pragma unroll
    for (int to = 0; to < 4; ++to) {
        const f32x4 bf4 = *(const f32x4*)(wsf + WS_BF + to*16 + lg*4);
#pragma unroll
        for (int tt = 0; tt < 4; ++tt) acc[to][tt] = bf4;
    }
    {
#pragma unroll
        for (int s = 0; s < 2; ++s) {
            f16x8 A0 = *(const f16x8*)(wsA2 + ((s+2)*4+0)*512 + l*8);
            f16x8 A1 = *(const f16x8*)(wsA2 + ((s+2)*4+1)*512 + l*8);
            f16x8 A2 = *(const f16x8*)(wsA2 + ((s+2)*4+2)*512 + l*8);
            f16x8 A3 = *(const f16x8*)(wsA2 + ((s+2)*4+3)*512 + l*8);
#pragma unroll
            for (int tt = 0; tt < 4; ++tt) {
                const f16x8 B = *(const f16x8*)(sb + (s*4+lg)*1024 + (tt*16+li)*16);
                acc[0][tt] = __builtin_amdgcn_mfma_f32_16x16x32_f16(A0, B, acc[0][tt], 0, 0, 0);
                acc[1][tt] = __builtin_amdgcn_mfma_f32_16x16x32_f16(A1, B, acc[1][tt], 0, 0, 0);
                acc[2][tt] = __builtin_amdgcn_mfma_f32_16x16x32_f16(A2, B, acc[2][tt], 0, 0, 0);
                acc[3][tt] = __builtin_amdgcn_mfma_f32_16x16x32_f16(A3, B, acc[3][tt], 0, 0, 0);
            }
        }
    }
    __syncthreads();                                      // R->W: done reading u_ps

    // ---- conv store: u_conv[row][o] from cu -> slots 0..7 (same map as ps pack) ----
#pragma unroll
    for (int to = 0; to < 4; ++to)
#pragma unroll
        for (int tt = 0; tt < 4; ++tt) {
            uint32x2 w = { cu[(to*4+tt)*2+0], cu[(to*4+tt)*2+1] };
            *(uint32x2*)(sb + (to*2+(lg>>1))*1024 + (tt*16+li)*16 + ((lg&1)<<3)) = w;
        }
    __syncthreads();                                      // W->R: u_conv ready

    // ---- GEMM2-conv: acc += Wf_lo^T u_conv  (A2 frags q = 0..7, slots 0..7) ----
    {
#pragma unroll
        for (int s = 0; s < 2; ++s) {
            f16x8 A0 = *(const f16x8*)(wsA2 + (s*4+0)*512 + l*8);
            f16x8 A1 = *(const f16x8*)(wsA2 + (s*4+1)*512 + l*8);
            f16x8 A2 = *(const f16x8*)(wsA2 + (s*4+2)*512 + l*8);
            f16x8 A3 = *(const f16x8*)(wsA2 + (s*4+3)*512 + l*8);
#pragma unroll
            for (int tt = 0; tt < 4; ++tt) {
                const f16x8 B = *(const f16x8*)(sb + (s*4+lg)*1024 + (tt*16+li)*16);
                acc[0][tt] = __builtin_amdgcn_mfma_f32_16x16x32_f16(A0, B, acc[0][tt], 0, 0, 0);
                acc[1][tt] = __builtin_amdgcn_mfma_f32_16x16x32_f16(A1, B, acc[1][tt], 0, 0, 0);
                acc[2][tt] = __builtin_amdgcn_mfma_f32_16x16x32_f16(A2, B, acc[2][tt], 0, 0, 0);
                acc[3][tt] = __builtin_amdgcn_mfma_f32_16x16x32_f16(A3, B, acc[3][tt], 0, 0, 0);
            }
        }
    }

    // ---- final epilogue: relu (bias already in C-init), store out[b][o][j][t] ----
#pragma unroll
    for (int to = 0; to < 4; ++to) {
#pragma unroll
        for (int tt = 0; tt < 4; ++tt) {
            const int tg = blockIdx.x*64 + tt*16 + li;
#pragma unroll
            for (int r = 0; r < 4; ++r) {
                const int o = to*16 + lg*4 + r;
                out[(((size_t)b*64 + o)*64 + j)*256 + tg] = fmaxf(acc[to][tt][r], 0.f);
            }
        }
    }
}

extern "C" void kernel_launch(void* const* d_in, const int* in_sizes, int n_in,
                              void* d_out, int out_size, void* d_ws, size_t ws_size,
                              hipStream_t stream)
{
    const float* x      = (const float*)d_in[0];
    const int*   path   = (const int*)  d_in[1];
    const float* W_ssig = (const float*)d_in[2];
    const float* b_ssig = (const float*)d_in[3];
    const float* W_tsig = (const float*)d_in[4];
    const float* b_tsig = (const float*)d_in[5];
    const float* W_raw  = (const float*)d_in[6];
    const float* b_raw  = (const float*)d_in[7];
    const float* W_ps   = (const float*)d_in[8];
    const float* b_ps   = (const float*)d_in[9];
    const float* W_fu   = (const float*)d_in[10];
    const float* b_fu   = (const float*)d_in[11];
    const float* g_raw  = (const float*)d_in[12];
    const float* be_raw = (const float*)d_in[13];
    const float* m_raw  = (const float*)d_in[14];
    const float* v_raw  = (const float*)d_in[15];
    const float* g_ps   = (const float*)d_in[16];
    const float* be_ps  = (const float*)d_in[17];
    const float* m_ps   = (const float*)d_in[18];
    const float* v_ps   = (const float*)d_in[19];
    const float* g_fu   = (const float*)d_in[20];
    const float* be_fu  = (const float*)d_in[21];
    const float* m_fu   = (const float*)d_in[22];
    const float* v_fu   = (const float*)d_in[23];
    float* out = (float*)d_out;

    float*          wsf  = (float*)d_ws;
    unsigned short* wsA1 = (unsigned short*)((char*)d_ws + 4096);
    unsigned short* wsA2 = (unsigned short*)((char*)d_ws + 28672);
    unsigned short* wsA3 = (unsigned short*)((char*)d_ws + 45056);

    stem_prep<<<45, 64, 0, stream>>>(W_ssig, b_ssig, W_tsig, b_tsig, W_raw, b_raw,
                                     W_ps, b_ps, W_fu, b_fu,
                                     g_raw, be_raw, m_raw, v_raw,
                                     g_ps, be_ps, m_ps, v_ps,
                                     g_fu, be_fu, m_fu, v_fu, wsf, wsA1, wsA2, wsA3);

    dim3 grid(4, 64, 32);   // (t-chunks, J, B)
    stem_main<<<grid, 64, 0, stream>>>(x, path, wsf, wsA1, wsA2, wsA3, out);
}

// Round 16
// 60.450 us; speedup vs baseline: 1.4005x; 1.0019x over previous
//
#include <hip/hip_runtime.h>
#include <hip/hip_fp16.h>
#include <cstdint>

#define EPSF 1e-5f

typedef __attribute__((ext_vector_type(8))) _Float16  f16x8;
typedef __attribute__((ext_vector_type(4))) float     f32x4;
typedef __attribute__((ext_vector_type(4))) unsigned int uint32x4;
typedef __attribute__((ext_vector_type(2))) unsigned int uint32x2;

// ---- workspace layout ----
#define WS_B0 0
#define WS_BC 64
#define WS_BF 128
// f16 A-fragments: wsA1 @4096 (24*512), wsA2 @28672 (16*512), wsA3 @45056 (4*512, conv K=32)

__device__ __forceinline__ unsigned short f2h(float f) {
    __half h = __float2half(f);              // RNE
    return *reinterpret_cast<unsigned short*>(&h);
}

// f32 pair -> f16 pair (RTZ), single instruction
__device__ __forceinline__ unsigned cvtpk_h(float lo, float hi) {
    unsigned r;
    asm("v_cvt_pkrtz_f16_f32 %0, %1, %2" : "=v"(r) : "v"(lo), "v"(hi));
    return r;
}

// ---- packed f16 VOP3P helpers (TRUE dual-rate on CDNA; op_sel folds broadcasts) ----
__device__ __forceinline__ unsigned pkfma(unsigned a, unsigned b, unsigned c) {
    unsigned d; asm("v_pk_fma_f16 %0, %1, %2, %3" : "=v"(d) : "v"(a), "v"(b), "v"(c)); return d;
}
__device__ __forceinline__ unsigned pkfma_lo(unsigned a, unsigned b, unsigned c) {  // bcast a.lo
    unsigned d; asm("v_pk_fma_f16 %0, %1, %2, %3 op_sel_hi:[0,1,1]" : "=v"(d) : "v"(a), "v"(b), "v"(c)); return d;
}
__device__ __forceinline__ unsigned pkfma_hi(unsigned a, unsigned b, unsigned c) {  // bcast a.hi
    unsigned d; asm("v_pk_fma_f16 %0, %1, %2, %3 op_sel:[1,0,0]" : "=v"(d) : "v"(a), "v"(b), "v"(c)); return d;
}
__device__ __forceinline__ unsigned pkmul(unsigned a, unsigned b) {
    unsigned d; asm("v_pk_mul_f16 %0, %1, %2" : "=v"(d) : "v"(a), "v"(b)); return d;
}
__device__ __forceinline__ unsigned pkmul_lo(unsigned a, unsigned b) {
    unsigned d; asm("v_pk_mul_f16 %0, %1, %2 op_sel_hi:[0,1]" : "=v"(d) : "v"(a), "v"(b)); return d;
}
__device__ __forceinline__ unsigned pkmul_hi(unsigned a, unsigned b) {
    unsigned d; asm("v_pk_mul_f16 %0, %1, %2 op_sel:[1,0]" : "=v"(d) : "v"(a), "v"(b)); return d;
}
__device__ __forceinline__ unsigned pkadd(unsigned a, unsigned b) {
    unsigned d; asm("v_pk_add_f16 %0, %1, %2" : "=v"(d) : "v"(a), "v"(b)); return d;
}

#define C_HALF2  0x38003800u   // (0.5h, 0.5h)
#define C_THIRD2 0x35553555u   // (1/3 h, 1/3 h)

// ---------------- prep: fold BNs, collapse W_ps@{W_ssig,W_tsig}, pack MFMA A-frags (f16) ----------------
__global__ __launch_bounds__(64) void stem_prep(
    const float* __restrict__ W_ssig, const float* __restrict__ b_ssig,
    const float* __restrict__ W_tsig, const float* __restrict__ b_tsig,
    const float* __restrict__ W_raw,  const float* __restrict__ b_raw,
    const float* __restrict__ W_ps,   const float* __restrict__ b_ps,
    const float* __restrict__ W_fu,   const float* __restrict__ b_fu,
    const float* __restrict__ g_raw, const float* __restrict__ be_raw,
    const float* __restrict__ m_raw, const float* __restrict__ v_raw,
    const float* __restrict__ g_ps,  const float* __restrict__ be_ps,
    const float* __restrict__ m_ps,  const float* __restrict__ v_ps,
    const float* __restrict__ g_fu,  const float* __restrict__ be_fu,
    const float* __restrict__ m_fu,  const float* __restrict__ v_fu,
    float* __restrict__ wsf, unsigned short* __restrict__ wsA1,
    unsigned short* __restrict__ wsA2, unsigned short* __restrict__ wsA3)
{
    const int l = threadIdx.x;         // 0..63
    const int f = blockIdx.x;
    if (f < 24) {
        const int h = f / 12, rem = f % 12, s = rem / 4, to = rem % 4;
        const int o = to*16 + (l & 15);
        const float sps = g_ps[o] / sqrtf(v_ps[o] + EPSF);
        const float* wp  = W_ps + o*128 + 64*h;
        const float* wsg = h ? W_tsig : W_ssig;
        for (int b = 0; b < 8; ++b) {
            const int k = s*32 + ((l >> 4) * 8) + b;
            float v = 0.f;
            if (k < 84) {
                float acc = 0.f;
                for (int c = 0; c < 64; ++c) acc = fmaf(wp[c], wsg[c*84 + k], acc);
                v = acc * sps;
            }
            wsA1[f*512 + l*8 + b] = f2h(v);
        }
    } else if (f < 40) {
        const int q = f - 24, s = q / 4, to = q % 4;
        const int o = to*16 + (l & 15);
        const float sfu = g_fu[o] / sqrtf(v_fu[o] + EPSF);
        for (int b = 0; b < 8; ++b) {
            const int c = s*32 + ((l >> 4) * 8) + b;
            wsA2[q*512 + l*8 + b] = f2h(W_fu[o*128 + c] * sfu);
        }
    } else if (f == 40) {
        const int o = l;
        const float sps = g_ps[o] / sqrtf(v_ps[o] + EPSF);
        float acc = b_ps[o] - m_ps[o];
        for (int c = 0; c < 64; ++c) {
            acc = fmaf(W_ps[o*128 + c],      b_ssig[c], acc);
            acc = fmaf(W_ps[o*128 + 64 + c], b_tsig[c], acc);
        }
        wsf[WS_B0 + o] = acc * sps + be_ps[o];
        const float sraw = g_raw[o] / sqrtf(v_raw[o] + EPSF);
        wsf[WS_BC + o] = (b_raw[o] - m_raw[o]) * sraw + be_raw[o];
        const float sfu = g_fu[o] / sqrtf(v_fu[o] + EPSF);
        wsf[WS_BF + o] = (b_fu[o] - m_fu[o]) * sfu + be_fu[o];
    } else {
        const int to = f - 41;
        const int o = to*16 + (l & 15);
        const float sraw = g_raw[o] / sqrtf(v_raw[o] + EPSF);
        for (int b = 0; b < 8; ++b) {
            const int k = ((l >> 4) * 8) + b;
            wsA3[to*512 + l*8 + b] = (k < 9) ? f2h(W_raw[o*9 + k] * sraw) : (unsigned short)0;
        }
    }
}

// ---- packed-f16 factored sig step (56 pk insts). S[42]: S1=S[0..1], S2=S[2..9], S3=S[10..41].
__device__ __forceinline__ void sig_step_h(unsigned* __restrict__ S, unsigned d01, unsigned d23)
{
    const unsigned dh0 = pkmul(C_HALF2, d01), dh1 = pkmul(C_HALF2, d23);
    const unsigned fv0 = pkfma(d01, C_THIRD2, S[0]);
    const unsigned fv1 = pkfma(d23, C_THIRD2, S[1]);
    unsigned h[8];                                // h[i*2+p], OLD S2
    h[0] = pkfma_lo(fv0, dh0, S[2]); h[1] = pkfma_lo(fv0, dh1, S[3]);
    h[2] = pkfma_hi(fv0, dh0, S[4]); h[3] = pkfma_hi(fv0, dh1, S[5]);
    h[4] = pkfma_lo(fv1, dh0, S[6]); h[5] = pkfma_lo(fv1, dh1, S[7]);
    h[6] = pkfma_hi(fv1, dh0, S[8]); h[7] = pkfma_hi(fv1, dh1, S[9]);
#pragma unroll
    for (int i = 0; i < 4; ++i) {
#pragma unroll
        for (int j = 0; j < 4; ++j) {
            const int hr = i*2 + (j>>1);
            const int base = 10 + (i*4+j)*2;
            if (j & 1) { S[base]   = pkfma_hi(h[hr], d01, S[base]);
                         S[base+1] = pkfma_hi(h[hr], d23, S[base+1]); }
            else       { S[base]   = pkfma_lo(h[hr], d01, S[base]);
                         S[base+1] = pkfma_lo(h[hr], d23, S[base+1]); }
        }
    }
    const unsigned q0 = pkadd(S[0], dh0), q1 = pkadd(S[1], dh1);   // OLD S1
    S[2] = pkfma_lo(q0, d01, S[2]); S[3] = pkfma_lo(q0, d23, S[3]);
    S[4] = pkfma_hi(q0, d01, S[4]); S[5] = pkfma_hi(q0, d23, S[5]);
    S[6] = pkfma_lo(q1, d01, S[6]); S[7] = pkfma_lo(q1, d23, S[7]);
    S[8] = pkfma_hi(q1, d01, S[8]); S[9] = pkfma_hi(q1, d23, S[9]);
    S[0] = pkadd(S[0], d01); S[1] = pkadd(S[1], d23);
}

// first step from zero state (d3==0 in d23.hi): S1=d, S2=dh_i*d_j, S3=(d_i/3)*S2[jk]
__device__ __forceinline__ void sig_init_h(unsigned* __restrict__ S, unsigned d01, unsigned d23)
{
    S[0] = d01; S[1] = d23;
    const unsigned dh0 = pkmul(C_HALF2, d01), dh1 = pkmul(C_HALF2, d23);
    S[2] = pkmul_lo(dh0, d01); S[3] = pkmul_lo(dh0, d23);
    S[4] = pkmul_hi(dh0, d01); S[5] = pkmul_hi(dh0, d23);
    S[6] = pkmul_lo(dh1, d01); S[7] = pkmul_lo(dh1, d23);
    S[8] = pkmul_hi(dh1, d01); S[9] = pkmul_hi(dh1, d23);
    const unsigned td0 = pkmul(C_THIRD2, d01), td1 = pkmul(C_THIRD2, d23);
#pragma unroll
    for (int i = 0; i < 4; ++i) {
        const unsigned tdr = (i < 2) ? td0 : td1;
#pragma unroll
        for (int j = 0; j < 4; ++j) {
            const int base = 10 + (i*4+j)*2;
            if (i & 1) { S[base]   = pkmul_hi(tdr, S[2+j*2]);
                         S[base+1] = pkmul_hi(tdr, S[2+j*2+1]); }
            else       { S[base]   = pkmul_lo(tdr, S[2+j*2]);
                         S[base+1] = pkmul_lo(tdr, S[2+j*2+1]); }
        }
    }
}

// grid: (4 t-chunks, 64 j, 32 b); block 64 = 1 wave. k-major LDS: slot s at byte
// s*1024 + row*16; 12 slots = 12288 B. EXACT round-13 structure (__syncthreads at
// every LDS phase boundary -- rounds 14/15 showed the "cheaper fence" bundle breaks
// correctness; reverted). Added: s_setprio(1) around MFMA clusters (T5 -- pays for
// independent 1-wave blocks at different phases; zero correctness risk).
__global__ __launch_bounds__(64, 3) void stem_main(
    const float* __restrict__ x, const int* __restrict__ path,
    const float* __restrict__ wsf, const unsigned short* __restrict__ wsA1,
    const unsigned short* __restrict__ wsA2, const unsigned short* __restrict__ wsA3,
    float* __restrict__ out)
{
    __shared__ char sb[12 * 1024];
    const int l  = threadIdx.x;                  // lane
    const int t  = blockIdx.x * 64 + l;          // global t for this thread's column
    const int j  = blockIdx.y;
    const int b  = blockIdx.z;
    const float* xb = x + (size_t)b * (3*64*256);

    const int lg = l >> 4;      // lane k-group
    const int li = l & 15;      // m/n index within tile
    char* const myw = sb + l*16;                 // write base: slot via immediate

    // ==== issue ALL sigma input loads up front (addresses depend only on j,t) ====
    float ps_[5][3];
#pragma unroll
    for (int s = 0; s < 5; ++s) {
        const int jp = path[j*5 + s];             // wave-uniform
        ps_[s][0] = xb[(0*64 + jp)*256 + t];
        ps_[s][1] = xb[(1*64 + jp)*256 + t];
        ps_[s][2] = xb[(2*64 + jp)*256 + t];
    }
    float pt_[7][3];
#pragma unroll
    for (int k = 0; k < 7; ++k) {
        const int idx  = j*7 + k;
        const int jsrc = idx & 63;
        const int tl   = idx >> 6;
        const int ts   = min(max(t + tl - 3, 0), 255);
        pt_[k][0] = xb[(0*64 + jsrc)*256 + ts];
        pt_[k][1] = xb[(1*64 + jsrc)*256 + ts];
        pt_[k][2] = xb[(2*64 + jsrc)*256 + ts];
    }

    unsigned S[42];

    // ---- sigma_s: init (d3=0), then 4 steps with d3 = 0.25 ----
    sig_init_h(S, cvtpk_h(ps_[0][0], ps_[0][1]), cvtpk_h(ps_[0][2], 0.f));
#pragma unroll
    for (int s = 1; s < 5; ++s) {
        const unsigned d01 = cvtpk_h(ps_[s][0]-ps_[s-1][0], ps_[s][1]-ps_[s-1][1]);
        const unsigned d23 = cvtpk_h(ps_[s][2]-ps_[s-1][2], 0.25f);
        sig_step_h(S, d01, d23);
    }
    // store sigma_s DIRECTLY (f16 pairs, linear k): slots 0..9 full, 10 half, 11 zero
    {
#pragma unroll
        for (int v = 0; v < 10; ++v) {
            uint32x4 w = { S[4*v], S[4*v+1], S[4*v+2], S[4*v+3] };
            *(uint32x4*)(myw + v*1024) = w;
        }
        uint32x4 w10 = { S[40], S[41], 0u, 0u }; *(uint32x4*)(myw + 10*1024) = w10;
        uint32x4 w11 = { 0u, 0u, 0u, 0u };       *(uint32x4*)(myw + 11*1024) = w11;
    }
    __syncthreads();                                      // W->R: sigma_s ready

    // ---- sigma_t NOW (before acc is born); state stays in S regs across GEMM1a ----
    sig_init_h(S, cvtpk_h(pt_[0][0], pt_[0][1]), cvtpk_h(pt_[0][2], 0.f));
#pragma unroll
    for (int k = 1; k < 7; ++k) {
        const unsigned d01 = cvtpk_h(pt_[k][0]-pt_[k-1][0], pt_[k][1]-pt_[k-1][1]);
        const unsigned d23 = cvtpk_h(pt_[k][2]-pt_[k-1][2], (1.f/6.f));
        sig_step_h(S, d01, d23);
    }

    // ---- GEMM1a: acc = B0 + A(h=0) * sigma_s ----
    f32x4 acc[4][4];
#pragma unroll
    for (int to = 0; to < 4; ++to) {
        const f32x4 b0 = *(const f32x4*)(wsf + WS_B0 + to*16 + lg*4);
#pragma unroll
        for (int tt = 0; tt < 4; ++tt) acc[to][tt] = b0;
    }
    __builtin_amdgcn_s_setprio(1);
    {
#pragma unroll
        for (int s = 0; s < 3; ++s) {
            f16x8 A0 = *(const f16x8*)(wsA1 + ((0*3+s)*4+0)*512 + l*8);
            f16x8 A1 = *(const f16x8*)(wsA1 + ((0*3+s)*4+1)*512 + l*8);
            f16x8 A2 = *(const f16x8*)(wsA1 + ((0*3+s)*4+2)*512 + l*8);
            f16x8 A3 = *(const f16x8*)(wsA1 + ((0*3+s)*4+3)*512 + l*8);
#pragma unroll
            for (int tt = 0; tt < 4; ++tt) {
                const f16x8 B = *(const f16x8*)(sb + (s*4+lg)*1024 + (tt*16+li)*16);
                acc[0][tt] = __builtin_amdgcn_mfma_f32_16x16x32_f16(A0, B, acc[0][tt], 0, 0, 0);
                acc[1][tt] = __builtin_amdgcn_mfma_f32_16x16x32_f16(A1, B, acc[1][tt], 0, 0, 0);
                acc[2][tt] = __builtin_amdgcn_mfma_f32_16x16x32_f16(A2, B, acc[2][tt], 0, 0, 0);
                acc[3][tt] = __builtin_amdgcn_mfma_f32_16x16x32_f16(A3, B, acc[3][tt], 0, 0, 0);
            }
        }
    }
    __builtin_amdgcn_s_setprio(0);
    __syncthreads();                                      // R->W: done reading sigma_s

    // dump sigma_t state -> LDS slots 0..10 (slot 11 zeros persist)
    {
#pragma unroll
        for (int v = 0; v < 10; ++v) {
            uint32x4 w = { S[4*v], S[4*v+1], S[4*v+2], S[4*v+3] };
            *(uint32x4*)(myw + v*1024) = w;
        }
        uint32x4 w10 = { S[40], S[41], 0u, 0u }; *(uint32x4*)(myw + 10*1024) = w10;
    }
    __syncthreads();                                      // W->R: sigma_t ready

    // conv window loads issued here (HBM latency hides under GEMM1b)
    float xv[9];
#pragma unroll
    for (int ci = 0; ci < 3; ++ci) {
        const float* xr = xb + (ci*64 + j)*256;
        xv[ci*3+0] = (t >= 1)   ? xr[t-1] : 0.f;
        xv[ci*3+1] = xr[t];
        xv[ci*3+2] = (t <= 254) ? xr[t+1] : 0.f;
    }

    // ---- GEMM1b: acc += A(h=1) * sigma_t ----
    __builtin_amdgcn_s_setprio(1);
    {
#pragma unroll
        for (int s = 0; s < 3; ++s) {
            f16x8 A0 = *(const f16x8*)(wsA1 + ((1*3+s)*4+0)*512 + l*8);
            f16x8 A1 = *(const f16x8*)(wsA1 + ((1*3+s)*4+1)*512 + l*8);
            f16x8 A2 = *(const f16x8*)(wsA1 + ((1*3+s)*4+2)*512 + l*8);
            f16x8 A3 = *(const f16x8*)(wsA1 + ((1*3+s)*4+3)*512 + l*8);
#pragma unroll
            for (int tt = 0; tt < 4; ++tt) {
                const f16x8 B = *(const f16x8*)(sb + (s*4+lg)*1024 + (tt*16+li)*16);
                acc[0][tt] = __builtin_amdgcn_mfma_f32_16x16x32_f16(A0, B, acc[0][tt], 0, 0, 0);
                acc[1][tt] = __builtin_amdgcn_mfma_f32_16x16x32_f16(A1, B, acc[1][tt], 0, 0, 0);
                acc[2][tt] = __builtin_amdgcn_mfma_f32_16x16x32_f16(A2, B, acc[2][tt], 0, 0, 0);
                acc[3][tt] = __builtin_amdgcn_mfma_f32_16x16x32_f16(A3, B, acc[3][tt], 0, 0, 0);
            }
        }
    }
    __builtin_amdgcn_s_setprio(0);
    __syncthreads();                                      // R->W: done reading sigma_t

    // ---- ps pack: u_ps[row][o] = f16(relu(acc)) via f32 fmax + cvtpk, slots 0..7 ----
#pragma unroll
    for (int to = 0; to < 4; ++to) {
#pragma unroll
        for (int tt = 0; tt < 4; ++tt) {
            const unsigned w0 = cvtpk_h(fmaxf(acc[to][tt][0], 0.f), fmaxf(acc[to][tt][1], 0.f));
            const unsigned w1 = cvtpk_h(fmaxf(acc[to][tt][2], 0.f), fmaxf(acc[to][tt][3], 0.f));
            uint32x2 w = { w0, w1 };
            *(uint32x2*)(sb + (to*2+(lg>>1))*1024 + (tt*16+li)*16 + ((lg&1)<<3)) = w;
        }
    }
    // ---- xv pack (f16) -> slots 8..11 (K=32, zeros beyond k=8) ----
    {
        unsigned xu[16];
        xu[0] = cvtpk_h(xv[0], xv[1]); xu[1] = cvtpk_h(xv[2], xv[3]);
        xu[2] = cvtpk_h(xv[4], xv[5]); xu[3] = cvtpk_h(xv[6], xv[7]);
        xu[4] = cvtpk_h(xv[8], 0.f);
#pragma unroll
        for (int i = 5; i < 16; ++i) xu[i] = 0u;
#pragma unroll
        for (int v = 0; v < 4; ++v) {
            uint32x4 w = { xu[4*v], xu[4*v+1], xu[4*v+2], xu[4*v+3] };
            *(uint32x4*)(myw + (8+v)*1024) = w;
        }
    }
    __syncthreads();                                      // W->R: u_ps + xv ready

    // ---- GEMM-conv via MFMA: acc = BC + Wc * xv  (K=32, slots 8..11, A3 frags) ----
#pragma unroll
    for (int to = 0; to < 4; ++to) {
        const f32x4 bc4 = *(const f32x4*)(wsf + WS_BC + to*16 + lg*4);
#pragma unroll
        for (int tt = 0; tt < 4; ++tt) acc[to][tt] = bc4;
    }
    __builtin_amdgcn_s_setprio(1);
    {
        f16x8 A0 = *(const f16x8*)(wsA3 + 0*512 + l*8);
        f16x8 A1 = *(const f16x8*)(wsA3 + 1*512 + l*8);
        f16x8 A2 = *(const f16x8*)(wsA3 + 2*512 + l*8);
        f16x8 A3 = *(const f16x8*)(wsA3 + 3*512 + l*8);
#pragma unroll
        for (int tt = 0; tt < 4; ++tt) {
            const f16x8 B = *(const f16x8*)(sb + (8+lg)*1024 + (tt*16+li)*16);
            acc[0][tt] = __builtin_amdgcn_mfma_f32_16x16x32_f16(A0, B, acc[0][tt], 0, 0, 0);
            acc[1][tt] = __builtin_amdgcn_mfma_f32_16x16x32_f16(A1, B, acc[1][tt], 0, 0, 0);
            acc[2][tt] = __builtin_amdgcn_mfma_f32_16x16x32_f16(A2, B, acc[2][tt], 0, 0, 0);
            acc[3][tt] = __builtin_amdgcn_mfma_f32_16x16x32_f16(A3, B, acc[3][tt], 0, 0, 0);
        }
    }
    __builtin_amdgcn_s_setprio(0);
    // relu-pack conv result to regs (same [row][o] mapping as ps pack)
    unsigned cu[32];
#pragma unroll
    for (int to = 0; to < 4; ++to)
#pragma unroll
        for (int tt = 0; tt < 4; ++tt) {
            cu[(to*4+tt)*2+0] = cvtpk_h(fmaxf(acc[to][tt][0], 0.f), fmaxf(acc[to][tt][1], 0.f));
            cu[(to*4+tt)*2+1] = cvtpk_h(fmaxf(acc[to][tt][2], 0.f), fmaxf(acc[to][tt][3], 0.f));
        }

    // ---- GEMM2-ps: acc = BF + Wf_hi^T u_ps  (A2 frags q = 8..15, slots 0..7) ----
#pragma unroll
    for (int to = 0; to < 4; ++to) {
        const f32x4 bf4 = *(const f32x4*)(wsf + WS_BF + to*16 + lg*4);
#pragma unroll
        for (int tt = 0; tt < 4; ++tt) acc[to][tt] = bf4;
    }
    __builtin_amdgcn_s_setprio(1);
    {
#pragma unroll
        for (int s = 0; s < 2; ++s) {
            f16x8 A0 = *(const f16x8*)(wsA2 + ((s+2)*4+0)*512 + l*8);
            f16x8 A1 = *(const f16x8*)(wsA2 + ((s+2)*4+1)*512 + l*8);
            f16x8 A2 = *(const f16x8*)(wsA2 + ((s+2)*4+2)*512 + l*8);
            f16x8 A3 = *(const f16x8*)(wsA2 + ((s+2)*4+3)*512 + l*8);
#pragma unroll
            for (int tt = 0; tt < 4; ++tt) {
                const f16x8 B = *(const f16x8*)(sb + (s*4+lg)*1024 + (tt*16+li)*16);
                acc[0][tt] = __builtin_amdgcn_mfma_f32_16x16x32_f16(A0, B, acc[0][tt], 0, 0, 0);
                acc[1][tt] = __builtin_amdgcn_mfma_f32_16x16x32_f16(A1, B, acc[1][tt], 0, 0, 0);
                acc[2][tt] = __builtin_amdgcn_mfma_f32_16x16x32_f16(A2, B, acc[2][tt], 0, 0, 0);
                acc[3][tt] = __builtin_amdgcn_mfma_f32_16x16x32_f16(A3, B, acc[3][tt], 0, 0, 0);
            }
        }
    }
    __builtin_amdgcn_s_setprio(0);
    __syncthreads();                                      // R->W: done reading u_ps

    // ---- conv store: u_conv[row][o] from cu -> slots 0..7 ----
#pragma unroll
    for (int to = 0; to < 4; ++to)
#pragma unroll
        for (int tt = 0; tt < 4; ++tt) {
            uint32x2 w = { cu[(to*4+tt)*2+0], cu[(to*4+tt)*2+1] };
            *(uint32x2*)(sb + (to*2+(lg>>1))*1024 + (tt*16+li)*16 + ((lg&1)<<3)) = w;
        }
    __syncthreads();                                      // W->R: u_conv ready

    // ---- GEMM2-conv: acc += Wf_lo^T u_conv  (A2 frags q = 0..7, slots 0..7) ----
    __builtin_amdgcn_s_setprio(1);
    {
#pragma unroll
        for (int s = 0; s < 2; ++s) {
            f16x8 A0 = *(const f16x8*)(wsA2 + (s*4+0)*512 + l*8);
            f16x8 A1 = *(const f16x8*)(wsA2 + (s*4+1)*512 + l*8);
            f16x8 A2 = *(const f16x8*)(wsA2 + (s*4+2)*512 + l*8);
            f16x8 A3 = *(const f16x8*)(wsA2 + (s*4+3)*512 + l*8);
#pragma unroll
            for (int tt = 0; tt < 4; ++tt) {
                const f16x8 B = *(const f16x8*)(sb + (s*4+lg)*1024 + (tt*16+li)*16);
                acc[0][tt] = __builtin_amdgcn_mfma_f32_16x16x32_f16(A0, B, acc[0][tt], 0, 0, 0);
                acc[1][tt] = __builtin_amdgcn_mfma_f32_16x16x32_f16(A1, B, acc[1][tt], 0, 0, 0);
                acc[2][tt] = __builtin_amdgcn_mfma_f32_16x16x32_f16(A2, B, acc[2][tt], 0, 0, 0);
                acc[3][tt] = __builtin_amdgcn_mfma_f32_16x16x32_f16(A3, B, acc[3][tt], 0, 0, 0);
            }
        }
    }
    __builtin_amdgcn_s_setprio(0);

    // ---- final epilogue: relu (bias already in C-init), store out[b][o][j][t] ----
#pragma unroll
    for (int to = 0; to < 4; ++to) {
#pragma unroll
        for (int tt = 0; tt < 4; ++tt) {
            const int tg = blockIdx.x*64 + tt*16 + li;
#pragma unroll
            for (int r = 0; r < 4; ++r) {
                const int o = to*16 + lg*4 + r;
                out[(((size_t)b*64 + o)*64 + j)*256 + tg] = fmaxf(acc[to][tt][r], 0.f);
            }
        }
    }
}

extern "C" void kernel_launch(void* const* d_in, const int* in_sizes, int n_in,
                              void* d_out, int out_size, void* d_ws, size_t ws_size,
                              hipStream_t stream)
{
    const float* x      = (const float*)d_in[0];
    const int*   path   = (const int*)  d_in[1];
    const float* W_ssig = (const float*)d_in[2];
    const float* b_ssig = (const float*)d_in[3];
    const float* W_tsig = (const float*)d_in[4];
    const float* b_tsig = (const float*)d_in[5];
    const float* W_raw  = (const float*)d_in[6];
    const float* b_raw  = (const float*)d_in[7];
    const float* W_ps   = (const float*)d_in[8];
    const float* b_ps   = (const float*)d_in[9];
    const float* W_fu   = (const float*)d_in[10];
    const float* b_fu   = (const float*)d_in[11];
    const float* g_raw  = (const float*)d_in[12];
    const float* be_raw = (const float*)d_in[13];
    const float* m_raw  = (const float*)d_in[14];
    const float* v_raw  = (const float*)d_in[15];
    const float* g_ps   = (const float*)d_in[16];
    const float* be_ps  = (const float*)d_in[17];
    const float* m_ps   = (const float*)d_in[18];
    const float* v_ps   = (const float*)d_in[19];
    const float* g_fu   = (const float*)d_in[20];
    const float* be_fu  = (const float*)d_in[21];
    const float* m_fu   = (const float*)d_in[22];
    const float* v_fu   = (const float*)d_in[23];
    float* out = (float*)d_out;

    float*          wsf  = (float*)d_ws;
    unsigned short* wsA1 = (unsigned short*)((char*)d_ws + 4096);
    unsigned short* wsA2 = (unsigned short*)((char*)d_ws + 28672);
    unsigned short* wsA3 = (unsigned short*)((char*)d_ws + 45056);

    stem_prep<<<45, 64, 0, stream>>>(W_ssig, b_ssig, W_tsig, b_tsig, W_raw, b_raw,
                                     W_ps, b_ps, W_fu, b_fu,
                                     g_raw, be_raw, m_raw, v_raw,
                                     g_ps, be_ps, m_ps, v_ps,
                                     g_fu, be_fu, m_fu, v_fu, wsf, wsA1, wsA2, wsA3);

    dim3 grid(4, 64, 32);   // (t-chunks, J, B)
    stem_main<<<grid, 64, 0, stream>>>(x, path, wsf, wsA1, wsA2, wsA3, out);
}